// Round 14
// baseline (516.984 us; speedup 1.0000x reference)
//
#include <hip/hip_runtime.h>
#include <hip/hip_bf16.h>
#include <math.h>

#define T_TOK 4096
#define D_DIM 1024
#define E_EXP 8
#define FF_DIM 4096
#define NROWS (T_TOK * 2)
#define MAXT1 40   // max m-tiles (BM=256): 8192/256 + 8
#define MAXT2 72   // max m-tiles (BM=128): 8192/128 + 8

typedef unsigned short u16;
typedef unsigned int u32;
typedef __attribute__((ext_vector_type(8))) short bf16x8;
typedef __attribute__((ext_vector_type(4))) float f32x4;
typedef __attribute__((ext_vector_type(2))) unsigned int u32x2;

__device__ __forceinline__ u16 f2bf(float f) {
    union { float f; unsigned u; } v; v.f = f;
    unsigned r = v.u + 0x7FFFu + ((v.u >> 16) & 1u);
    return (u16)(r >> 16);
}

typedef const __attribute__((address_space(1))) u32* gas1_t;
typedef __attribute__((address_space(3))) u32* las3_t;
#define GLOAD16(g, l) __builtin_amdgcn_global_load_lds((gas1_t)(const void*)(g), (las3_t)(void*)(l), 16, 0, 0)
#define MFMA(a, b, c) __builtin_amdgcn_mfma_f32_16x16x32_bf16((a), (b), (c), 0, 0, 0)
#define CVTPK(dst, lo, hi) asm("v_cvt_pk_bf16_f32 %0, %1, %2" : "=v"(dst) : "v"(lo), "v"(hi))
#define CFENCE() asm volatile("" ::: "memory")
// sigma for B tiles: reads (16 consecutive rows) -> each value 2x = free;
// writes (rows stride 4) -> 8 distinct per 8-row sweep, <=4-way.
#define SIGB(r) (((r) ^ ((r) >> 2)) & 7)

// ---------------- small kernels ----------------

__global__ void k_init(int* cnt, float* probsum) {
    int i = threadIdx.x;
    if (i < E_EXP) { cnt[i] = 0; probsum[i] = 0.f; }
}

__global__ __launch_bounds__(256) void k_router(
    const float* __restrict__ x, const float* __restrict__ Wr,
    int* __restrict__ tok_e, float* __restrict__ tok_w,
    int* __restrict__ cnt, float* __restrict__ probsum)
{
    __shared__ float bp[E_EXP];
    __shared__ int   bc[E_EXP];
    const int tid = threadIdx.x;
    if (tid < E_EXP) { bp[tid] = 0.f; bc[tid] = 0; }
    __syncthreads();
    const int wave = tid >> 6, lane = tid & 63;
    const int t = blockIdx.x * 4 + wave;
    const float* xt = x + (size_t)t * D_DIM;
    float a[E_EXP] = {0.f,0.f,0.f,0.f,0.f,0.f,0.f,0.f};
    for (int j = lane; j < D_DIM; j += 64) {
        float xv = xt[j];
        #pragma unroll
        for (int e = 0; e < E_EXP; e++) a[e] = fmaf(xv, Wr[e * D_DIM + j], a[e]);
    }
    #pragma unroll
    for (int e = 0; e < E_EXP; e++) {
        #pragma unroll
        for (int off = 32; off; off >>= 1) a[e] += __shfl_xor(a[e], off, 64);
    }
    if (lane == 0) {
        float mx = a[0];
        #pragma unroll
        for (int e = 1; e < E_EXP; e++) mx = fmaxf(mx, a[e]);
        float p[E_EXP], s = 0.f;
        #pragma unroll
        for (int e = 0; e < E_EXP; e++) { p[e] = expf(a[e] - mx); s += p[e]; }
        float inv = 1.f / s;
        #pragma unroll
        for (int e = 0; e < E_EXP; e++) { p[e] *= inv; atomicAdd(&bp[e], p[e]); }
        int e0 = 0; float v0 = p[0];
        #pragma unroll
        for (int e = 1; e < E_EXP; e++) if (p[e] > v0) { v0 = p[e]; e0 = e; }
        int e1 = -1; float v1 = -1.f;
        #pragma unroll
        for (int e = 0; e < E_EXP; e++) if (e != e0 && p[e] > v1) { v1 = p[e]; e1 = e; }
        float sv = v0 + v1 + 1e-6f;
        tok_e[2*t] = e0; tok_e[2*t+1] = e1;
        tok_w[2*t] = v0 / sv; tok_w[2*t+1] = v1 / sv;
        atomicAdd(&bc[e0], 1); atomicAdd(&bc[e1], 1);
    }
    __syncthreads();
    if (tid < E_EXP) { atomicAdd(&cnt[tid], bc[tid]); atomicAdd(&probsum[tid], bp[tid]); }
}

__global__ void k_prefix(const int* __restrict__ cnt, const float* __restrict__ probsum,
                         int* __restrict__ basep, int* __restrict__ cursor,
                         float* __restrict__ out_lb,
                         int* __restrict__ nt1, int* __restrict__ te1, int* __restrict__ tm1,
                         int* __restrict__ nt2, int* __restrict__ te2, int* __restrict__ tm2)
{
    if (threadIdx.x == 0) {
        int b = 0; float lb = 0.f;
        for (int e = 0; e < E_EXP; e++) {
            basep[e] = b; b += cnt[e];
            lb += ((float)cnt[e] / (8192.f + 1e-6f)) * probsum[e];
        }
        *out_lb = lb * (float)E_EXP;
        int n1 = 0, n2 = 0;
        for (int e = 0; e < E_EXP; e++) {
            for (int m = 0; m < cnt[e]; m += 256) { te1[n1] = e; tm1[n1] = m; n1++; }
            for (int m = 0; m < cnt[e]; m += 128) { te2[n2] = e; tm2[n2] = m; n2++; }
        }
        *nt1 = n1; *nt2 = n2;
    }
    if (threadIdx.x < E_EXP) cursor[threadIdx.x] = 0;
}

__global__ void k_assign(const int* __restrict__ tok_e, const float* __restrict__ tok_w,
                         const int* __restrict__ basep, int* __restrict__ cursor,
                         int* __restrict__ row_token, int* __restrict__ row_slot,
                         float* __restrict__ row_weight)
{
    int t = blockIdx.x * blockDim.x + threadIdx.x;
    if (t >= T_TOK) return;
    #pragma unroll
    for (int k = 0; k < 2; k++) {
        int e = tok_e[2*t + k];
        int pos = basep[e] + atomicAdd(&cursor[e], 1);
        row_token[pos] = t; row_slot[pos] = k; row_weight[pos] = tok_w[2*t + k];
    }
}

__global__ __launch_bounds__(256) void k_cvt_x(const float* __restrict__ in, u16* __restrict__ out) {
    size_t i = ((size_t)blockIdx.x * 256 + threadIdx.x) * 8;
    f32x4 a = *(const f32x4*)(in + i);
    f32x4 b = *(const f32x4*)(in + i + 4);
    bf16x8 o;
    #pragma unroll
    for (int j = 0; j < 4; j++) { o[j] = (short)f2bf(a[j]); o[j + 4] = (short)f2bf(b[j]); }
    *(bf16x8*)(out + i) = o;
}

// ---------------- pass 1: hg = silu(x@Wg) * (x@W1) ----------------
// BM=256 BN=128 BK=64, 8 waves. W1/Wg consumed fp32 from [E][D][FF] (no prepass).
// Per tile: issue BOTH mats' f32x4 loads + A gloads BEFORE COMP(0) (latency under
// 64 MFMAs), cvt_pk + ds_write_b64 between COMP(0) and COMP(1), single drain+barrier.
// B swizzle SIGB(row)=(row^(row>>2))&7: reads 2-way free, writes <=4-way.
// A (xbf bf16) via global_load_lds, sigma_A(r)=r&7 (R11-verified 0 conflicts).

__global__ __launch_bounds__(512, 2) void k_pass1(
    const u16* __restrict__ xbf,
    const float* __restrict__ W1, const float* __restrict__ Wg,
    const float* __restrict__ b1v, const float* __restrict__ bgv,
    const int* __restrict__ cnt, const int* __restrict__ basep,
    const int* __restrict__ row_token,
    const int* __restrict__ ntp, const int* __restrict__ te, const int* __restrict__ tm,
    u16* __restrict__ hg)
{
    const int ty = blockIdx.y;
    if (ty >= *ntp) return;
    const int e = te[ty];
    const int m0 = tm[ty];
    const int count = cnt[e];
    const int rbase = basep[e];
    const int n0 = blockIdx.x * 128;

    // per buffer (32768 elems = 64KB): A[256x64] @0, Bh[128x64] @16384, Bg @24576
    __shared__ __align__(16) u16 LDS[2 * 32768];

    const int tid = threadIdx.x;
    const int l = tid & 63;
    const int w = tid >> 6;

    // ---- A staging ----
    const int rb = tid >> 3;
    const int swA = ((tid & 7) ^ ((tid >> 3) & 7)) * 8;
    const u16* sA[4];
    #pragma unroll
    for (int s = 0; s < 4; s++) {
        int g = m0 + rb + s * 64; if (g > count - 1) g = count - 1;
        sA[s] = xbf + (size_t)row_token[rbase + g] * D_DIM + swA;
    }

    // ---- B staging geometry: thread covers 4k x 4n per mat ----
    const int nq = tid & 31;           // n-quad: n = 4*nq .. +3
    const int kq = tid >> 5;           // 0..15: k = 4*kq .. +3 within tile
    const float* pBh = W1 + ((size_t)e * D_DIM + kq * 4) * FF_DIM + n0 + nq * 4;
    const float* pBg = Wg + ((size_t)e * D_DIM + kq * 4) * FF_DIM + n0 + nq * 4;
    const int cW = kq >> 1;            // 16B chunk of this thread's k-quad
    const int offW = (kq & 1) * 4;     // elem offset within chunk
    int wdst[4];
    #pragma unroll
    for (int j = 0; j < 4; j++) {
        const int row = nq * 4 + j;
        wdst[j] = row * 64 + (cW ^ SIGB(row)) * 8 + offW;
    }

    const int wm = w >> 2, wn = w & 3;   // 2M x 4N
    const int fr = l & 15, q = l >> 4;
    const int s7 = fr & 7;

    f32x4 acc_h[8][2], acc_g[8][2];
    const f32x4 z4 = {0.f, 0.f, 0.f, 0.f};
    #pragma unroll
    for (int mf = 0; mf < 8; mf++)
        #pragma unroll
        for (int nf = 0; nf < 2; nf++) { acc_h[mf][nf] = z4; acc_g[mf][nf] = z4; }

    f32x4 vh0, vh1, vh2, vh3, vg0, vg1, vg2, vg3;

    #define LOADH(K0) do { \
        const float* p_ = pBh + (size_t)(K0) * FF_DIM; \
        vh0 = *(const f32x4*)(p_); \
        vh1 = *(const f32x4*)(p_ + FF_DIM); \
        vh2 = *(const f32x4*)(p_ + 2 * FF_DIM); \
        vh3 = *(const f32x4*)(p_ + 3 * FF_DIM); \
    } while (0)
    #define LOADG(K0) do { \
        const float* p_ = pBg + (size_t)(K0) * FF_DIM; \
        vg0 = *(const f32x4*)(p_); \
        vg1 = *(const f32x4*)(p_ + FF_DIM); \
        vg2 = *(const f32x4*)(p_ + 2 * FF_DIM); \
        vg3 = *(const f32x4*)(p_ + 3 * FF_DIM); \
    } while (0)
    #define CVTH(BASE) do { \
        _Pragma("unroll") \
        for (int j = 0; j < 4; j++) { \
            u32 lo_, hi_; u32x2 wv_; \
            CVTPK(lo_, vh0[j], vh1[j]); \
            CVTPK(hi_, vh2[j], vh3[j]); \
            wv_.x = lo_; wv_.y = hi_; \
            *(u32x2*)&LDS[(BASE) + wdst[j]] = wv_; \
        } \
    } while (0)
    #define CVTG(BASE) do { \
        _Pragma("unroll") \
        for (int j = 0; j < 4; j++) { \
            u32 lo_, hi_; u32x2 wv_; \
            CVTPK(lo_, vg0[j], vg1[j]); \
            CVTPK(hi_, vg2[j], vg3[j]); \
            wv_.x = lo_; wv_.y = hi_; \
            *(u32x2*)&LDS[(BASE) + wdst[j]] = wv_; \
        } \
    } while (0)
    #define STAGE_A1(B, K0) do { \
        _Pragma("unroll") \
        for (int s = 0; s < 4; s++) \
            GLOAD16(sA[s] + (K0), &LDS[(B) * 32768 + s * 4096 + tid * 8]); \
    } while (0)

    auto COMP = [&](int kk, int ab) {
        const int rsA = ((kk * 4 + q) ^ s7) * 8;
        const int rB0 = wn * 32 + fr, rB1 = wn * 32 + 16 + fr;
        const int cb0 = ((kk * 4 + q) ^ SIGB(rB0)) * 8;
        const int cb1 = ((kk * 4 + q) ^ SIGB(rB1)) * 8;
        bf16x8 bh0 = *(const bf16x8*)&LDS[ab + 16384 + rB0 * 64 + cb0];
        bf16x8 bg0 = *(const bf16x8*)&LDS[ab + 24576 + rB0 * 64 + cb0];
        bf16x8 bh1 = *(const bf16x8*)&LDS[ab + 16384 + rB1 * 64 + cb1];
        bf16x8 bg1 = *(const bf16x8*)&LDS[ab + 24576 + rB1 * 64 + cb1];
        #define LDA1(i) (*(const bf16x8*)&LDS[ab + (wm * 128 + (i) * 16 + fr) * 64 + rsA])
        #define MF4(areg, i) do { \
            __builtin_amdgcn_s_setprio(1); \
            acc_h[i][0] = MFMA(areg, bh0, acc_h[i][0]); \
            acc_h[i][1] = MFMA(areg, bh1, acc_h[i][1]); \
            acc_g[i][0] = MFMA(areg, bg0, acc_g[i][0]); \
            acc_g[i][1] = MFMA(areg, bg1, acc_g[i][1]); \
            __builtin_amdgcn_s_setprio(0); } while (0)
        bf16x8 aA = LDA1(0);
        bf16x8 aB = LDA1(1);
        bf16x8 aC;
        aC = LDA1(2); MF4(aA, 0);
        aA = LDA1(3); MF4(aB, 1);
        aB = LDA1(4); MF4(aC, 2);
        aC = LDA1(5); MF4(aA, 3);
        aA = LDA1(6); MF4(aB, 4);
        aB = LDA1(7); MF4(aC, 5);
        MF4(aA, 6);
        MF4(aB, 7);
        #undef LDA1
        #undef MF4
    };

    const int NT = D_DIM / 64;   // 16
    // prologue: tile 0 -> buf 0
    LOADH(0); LOADG(0);
    STAGE_A1(0, 0);
    CVTH(16384); CVTG(24576);
    asm volatile("s_waitcnt vmcnt(0) lgkmcnt(0)" ::: "memory");
    __builtin_amdgcn_s_barrier();
    CFENCE();

    int b = 0;
    #pragma unroll 1
    for (int t = 0; t < NT; ++t) {
        const int ab = b * 32768;
        const int nboff = (b ^ 1) * 32768;
        const bool st = (t + 1 < NT);
        const int kN = (t + 1) * 64;
        if (st) {
            LOADH(kN); LOADG(kN);
            STAGE_A1(b ^ 1, kN);
        }
        COMP(0, ab);
        if (st) { CVTH(nboff + 16384); CVTG(nboff + 24576); }
        COMP(1, ab);
        asm volatile("s_waitcnt vmcnt(0) lgkmcnt(0)" ::: "memory");
        __builtin_amdgcn_s_barrier();
        CFENCE();
        b ^= 1;
    }
    #undef LOADH
    #undef LOADG
    #undef CVTH
    #undef CVTG
    #undef STAGE_A1

    const float* b1p = b1v + (size_t)e * FF_DIM + n0;
    const float* bgp = bgv + (size_t)e * FF_DIM + n0;
    #pragma unroll
    for (int mf = 0; mf < 8; mf++) {
        const int rl = wm * 128 + mf * 16 + q * 4;
        #pragma unroll
        for (int r = 0; r < 4; r++) {
            const int g = m0 + rl + r;
            if (g < count) {
                u16* orow = hg + (size_t)(rbase + g) * FF_DIM + n0;
                #pragma unroll
                for (int nf = 0; nf < 2; nf++) {
                    const int col = wn * 32 + nf * 16 + fr;
                    float hv = acc_h[mf][nf][r] + b1p[col];
                    float gv = acc_g[mf][nf][r] + bgp[col];
                    float sig = 1.f / (1.f + expf(-gv));
                    orow[col] = f2bf(gv * sig * hv);
                }
            }
        }
    }
}

// ---------------- pass 2: contrib[slot] = w * (hg @ W2 + b2) ----------------
// BM=128 BN=128 BK=64, 4 waves, 2x32KB dbuf -> 2 blocks/CU. W2 fp32 from
// [E][FF][D], fused transpose-convert with SIGB swizzle; loads before COMP(0),
// cvt between COMPs. A (hg bf16) via global_load_lds.

__global__ __launch_bounds__(256, 2) void k_pass2(
    const u16* __restrict__ hg,
    const float* __restrict__ W2, const float* __restrict__ b2v,
    const int* __restrict__ cnt, const int* __restrict__ basep,
    const int* __restrict__ row_token, const int* __restrict__ row_slot,
    const float* __restrict__ row_weight,
    const int* __restrict__ ntp, const int* __restrict__ te, const int* __restrict__ tm,
    float* __restrict__ contrib)
{
    const int ty = blockIdx.y;
    if (ty >= *ntp) return;
    const int e = te[ty];
    const int m0 = tm[ty];
    const int count = cnt[e];
    const int rbase = basep[e];
    const int n0 = blockIdx.x * 128;

    // per buffer (16384 elems = 32KB): A[128x64] @0, B[128x64] @8192
    __shared__ __align__(16) u16 LDS[2 * 16384];

    const int tid = threadIdx.x;
    const int l = tid & 63;
    const int w = tid >> 6;

    // A staging
    const int rb = tid >> 3;
    const int swA = ((tid & 7) ^ ((tid >> 3) & 7)) * 8;
    const u16* sA[4];
    #pragma unroll
    for (int s = 0; s < 4; s++) {
        int g = m0 + rb + s * 32; if (g > count - 1) g = count - 1;
        sA[s] = hg + (size_t)(rbase + g) * FF_DIM + swA;
    }

    // B staging: thread covers 8k x 4n (two 4k batches)
    const int nq = tid & 31;           // n = 4*nq .. +3
    const int koct = tid >> 5;         // 0..7: k = 8*koct .. +7
    const float* pB = W2 + ((size_t)e * FF_DIM + koct * 8) * D_DIM + n0 + nq * 4;
    int wdst[4];
    #pragma unroll
    for (int j = 0; j < 4; j++) {
        const int row = nq * 4 + j;
        wdst[j] = row * 64 + (koct ^ SIGB(row)) * 8;
    }

    const int wm = w >> 1, wn = w & 1;   // 2M x 2N
    const int fr = l & 15, q = l >> 4;
    const int s7 = fr & 7;

    f32x4 acc[4][4];
    const f32x4 z4 = {0.f, 0.f, 0.f, 0.f};
    #pragma unroll
    for (int mf = 0; mf < 4; mf++)
        #pragma unroll
        for (int nf = 0; nf < 4; nf++) acc[mf][nf] = z4;

    f32x4 va0, va1, va2, va3, vc0, vc1, vc2, vc3;

    #define LOADB0(K0) do { \
        const float* p_ = pB + (size_t)(K0) * D_DIM; \
        va0 = *(const f32x4*)(p_); \
        va1 = *(const f32x4*)(p_ + D_DIM); \
        va2 = *(const f32x4*)(p_ + 2 * D_DIM); \
        va3 = *(const f32x4*)(p_ + 3 * D_DIM); \
    } while (0)
    #define LOADB1X(K0) do { \
        const float* p_ = pB + (size_t)((K0) + 4) * D_DIM; \
        vc0 = *(const f32x4*)(p_); \
        vc1 = *(const f32x4*)(p_ + D_DIM); \
        vc2 = *(const f32x4*)(p_ + 2 * D_DIM); \
        vc3 = *(const f32x4*)(p_ + 3 * D_DIM); \
    } while (0)
    #define CVT0(BASE) do { \
        _Pragma("unroll") \
        for (int j = 0; j < 4; j++) { \
            u32 lo_, hi_; u32x2 wv_; \
            CVTPK(lo_, va0[j], va1[j]); \
            CVTPK(hi_, va2[j], va3[j]); \
            wv_.x = lo_; wv_.y = hi_; \
            *(u32x2*)&LDS[(BASE) + wdst[j]] = wv_; \
        } \
    } while (0)
    #define CVT1(BASE) do { \
        _Pragma("unroll") \
        for (int j = 0; j < 4; j++) { \
            u32 lo_, hi_; u32x2 wv_; \
            CVTPK(lo_, vc0[j], vc1[j]); \
            CVTPK(hi_, vc2[j], vc3[j]); \
            wv_.x = lo_; wv_.y = hi_; \
            *(u32x2*)&LDS[(BASE) + wdst[j] + 4] = wv_; \
        } \
    } while (0)
    #define STAGE_A2(B, K0) do { \
        _Pragma("unroll") \
        for (int s = 0; s < 4; s++) \
            GLOAD16(sA[s] + (K0), &LDS[(B) * 16384 + s * 2048 + tid * 8]); \
    } while (0)

    auto COMP = [&](int kk, int ab) {
        const int rsA = ((kk * 4 + q) ^ s7) * 8;
        bf16x8 a0, a1, a2, a3, bb0, bb1, bb2, bb3;
        {
            const int r0 = wn * 64 + fr, r1 = wn * 64 + 16 + fr;
            const int r2 = wn * 64 + 32 + fr, r3 = wn * 64 + 48 + fr;
            bb0 = *(const bf16x8*)&LDS[ab + 8192 + r0 * 64 + (((kk * 4 + q) ^ SIGB(r0)) * 8)];
            bb1 = *(const bf16x8*)&LDS[ab + 8192 + r1 * 64 + (((kk * 4 + q) ^ SIGB(r1)) * 8)];
            bb2 = *(const bf16x8*)&LDS[ab + 8192 + r2 * 64 + (((kk * 4 + q) ^ SIGB(r2)) * 8)];
            bb3 = *(const bf16x8*)&LDS[ab + 8192 + r3 * 64 + (((kk * 4 + q) ^ SIGB(r3)) * 8)];
        }
        a0 = *(const bf16x8*)&LDS[ab + (wm * 64 + 0 * 16 + fr) * 64 + rsA];
        a1 = *(const bf16x8*)&LDS[ab + (wm * 64 + 1 * 16 + fr) * 64 + rsA];
        a2 = *(const bf16x8*)&LDS[ab + (wm * 64 + 2 * 16 + fr) * 64 + rsA];
        a3 = *(const bf16x8*)&LDS[ab + (wm * 64 + 3 * 16 + fr) * 64 + rsA];
        __builtin_amdgcn_s_setprio(1);
        acc[0][0] = MFMA(a0, bb0, acc[0][0]); acc[0][1] = MFMA(a0, bb1, acc[0][1]);
        acc[0][2] = MFMA(a0, bb2, acc[0][2]); acc[0][3] = MFMA(a0, bb3, acc[0][3]);
        acc[1][0] = MFMA(a1, bb0, acc[1][0]); acc[1][1] = MFMA(a1, bb1, acc[1][1]);
        acc[1][2] = MFMA(a1, bb2, acc[1][2]); acc[1][3] = MFMA(a1, bb3, acc[1][3]);
        acc[2][0] = MFMA(a2, bb0, acc[2][0]); acc[2][1] = MFMA(a2, bb1, acc[2][1]);
        acc[2][2] = MFMA(a2, bb2, acc[2][2]); acc[2][3] = MFMA(a2, bb3, acc[2][3]);
        acc[3][0] = MFMA(a3, bb0, acc[3][0]); acc[3][1] = MFMA(a3, bb1, acc[3][1]);
        acc[3][2] = MFMA(a3, bb2, acc[3][2]); acc[3][3] = MFMA(a3, bb3, acc[3][3]);
        __builtin_amdgcn_s_setprio(0);
    };

    const int NT = FF_DIM / 64;   // 64
    LOADB0(0); LOADB1X(0);
    STAGE_A2(0, 0);
    CVT0(8192); CVT1(8192);
    asm volatile("s_waitcnt vmcnt(0) lgkmcnt(0)" ::: "memory");
    __builtin_amdgcn_s_barrier();
    CFENCE();

    int b = 0;
    #pragma unroll 1
    for (int t = 0; t < NT; ++t) {
        const int ab = b * 16384;
        const int nboff = (b ^ 1) * 16384;
        const bool st = (t + 1 < NT);
        const int kN = (t + 1) * 64;
        if (st) {
            LOADB0(kN); LOADB1X(kN);
            STAGE_A2(b ^ 1, kN);
        }
        COMP(0, ab);
        if (st) { CVT0(nboff + 8192); CVT1(nboff + 8192); }
        COMP(1, ab);
        asm volatile("s_waitcnt vmcnt(0) lgkmcnt(0)" ::: "memory");
        __builtin_amdgcn_s_barrier();
        CFENCE();
        b ^= 1;
    }
    #undef LOADB0
    #undef LOADB1X
    #undef CVT0
    #undef CVT1
    #undef STAGE_A2

    const float* b2p = b2v + (size_t)e * D_DIM + n0;
    #pragma unroll
    for (int mf = 0; mf < 4; mf++) {
        const int rl = wm * 64 + mf * 16 + q * 4;
        #pragma unroll
        for (int r = 0; r < 4; r++) {
            const int g = m0 + rl + r;
            if (g < count) {
                const int token = row_token[rbase + g];
                const int slot  = row_slot[rbase + g];
                const float wgt_ = row_weight[rbase + g];
                float* orow = contrib + ((size_t)slot * T_TOK + token) * D_DIM + n0;
                #pragma unroll
                for (int nf = 0; nf < 4; nf++) {
                    const int col = wn * 64 + nf * 16 + fr;
                    orow[col] = wgt_ * (acc[mf][nf][r] + b2p[col]);
                }
            }
        }
    }
}

__global__ void k_combine(const float* __restrict__ contrib, float* __restrict__ out) {
    int i = blockIdx.x * blockDim.x + threadIdx.x;
    const f32x4* c0 = (const f32x4*)contrib;
    const f32x4* c1 = c0 + ((size_t)T_TOK * D_DIM / 4);
    f32x4* o = (f32x4*)out;
    o[i] = c0[i] + c1[i];
}

// ---------------- launch ----------------

extern "C" void kernel_launch(void* const* d_in, const int* in_sizes, int n_in,
                              void* d_out, int out_size, void* d_ws, size_t ws_size,
                              hipStream_t stream)
{
    (void)in_sizes; (void)n_in; (void)out_size; (void)ws_size;
    const float* x  = (const float*)d_in[0];
    const float* Wr = (const float*)d_in[1];
    const float* W1 = (const float*)d_in[2];
    const float* b1 = (const float*)d_in[3];
    const float* Wg = (const float*)d_in[4];
    const float* bg = (const float*)d_in[5];
    const float* W2 = (const float*)d_in[6];
    const float* b2 = (const float*)d_in[7];
    float* out = (float*)d_out;

    char* ws = (char*)d_ws;
    u16* xbf = (u16*)ws;             ws += (size_t)T_TOK * D_DIM * sizeof(u16);
    u16* hg = (u16*)ws;              ws += (size_t)NROWS * FF_DIM * sizeof(u16);
    float* contrib = (float*)ws;     ws += (size_t)2 * T_TOK * D_DIM * sizeof(float);
    int* tok_e = (int*)ws;           ws += (size_t)T_TOK * 2 * sizeof(int);
    float* tok_w = (float*)ws;       ws += (size_t)T_TOK * 2 * sizeof(float);
    int* row_token = (int*)ws;       ws += (size_t)NROWS * sizeof(int);
    int* row_slot = (int*)ws;        ws += (size_t)NROWS * sizeof(int);
    float* row_weight = (float*)ws;  ws += (size_t)NROWS * sizeof(float);
    int* cnt = (int*)ws;             ws += 8 * sizeof(int);
    int* basep = (int*)ws;           ws += 8 * sizeof(int);
    int* cursor = (int*)ws;          ws += 8 * sizeof(int);
    float* probsum = (float*)ws;     ws += 8 * sizeof(float);
    int* nt1 = (int*)ws;             ws += sizeof(int);
    int* nt2 = (int*)ws;             ws += sizeof(int);
    int* te1 = (int*)ws;             ws += MAXT1 * sizeof(int);
    int* tm1 = (int*)ws;             ws += MAXT1 * sizeof(int);
    int* te2 = (int*)ws;             ws += MAXT2 * sizeof(int);
    int* tm2 = (int*)ws;             ws += MAXT2 * sizeof(int);

    k_init<<<1, 64, 0, stream>>>(cnt, probsum);
    k_cvt_x<<<(T_TOK * D_DIM / 8) / 256, 256, 0, stream>>>(x, xbf);
    k_router<<<T_TOK / 4, 256, 0, stream>>>(x, Wr, tok_e, tok_w, cnt, probsum);
    k_prefix<<<1, 64, 0, stream>>>(cnt, probsum, basep, cursor, out + (size_t)T_TOK * D_DIM,
                                   nt1, te1, tm1, nt2, te2, tm2);
    k_assign<<<T_TOK / 256, 256, 0, stream>>>(tok_e, tok_w, basep, cursor, row_token, row_slot, row_weight);
    k_pass1<<<dim3(FF_DIM / 128, MAXT1), 512, 0, stream>>>(xbf, W1, Wg, b1, bg, cnt, basep, row_token,
                                                           nt1, te1, tm1, hg);
    k_pass2<<<dim3(D_DIM / 128, MAXT2), 256, 0, stream>>>(hg, W2, b2, cnt, basep, row_token, row_slot, row_weight,
                                                          nt2, te2, tm2, contrib);
    k_combine<<<(T_TOK * D_DIM / 4) / 256, 256, 0, stream>>>(contrib, out);
}

// Round 15
// 502.113 us; speedup vs baseline: 1.0296x; 1.0296x over previous
//
#include <hip/hip_runtime.h>
#include <hip/hip_bf16.h>
#include <math.h>

#define T_TOK 4096
#define D_DIM 1024
#define E_EXP 8
#define FF_DIM 4096
#define NROWS (T_TOK * 2)
#define MAXT1 40   // max m-tiles (BM=256): 8192/256 + 8
#define MAXT2 72   // max m-tiles (BM=128): 8192/128 + 8

typedef unsigned short u16;
typedef unsigned int u32;
typedef __attribute__((ext_vector_type(8))) short bf16x8;
typedef __attribute__((ext_vector_type(4))) float f32x4;
typedef __attribute__((ext_vector_type(2))) unsigned int u32x2;

__device__ __forceinline__ u16 f2bf(float f) {
    union { float f; unsigned u; } v; v.f = f;
    unsigned r = v.u + 0x7FFFu + ((v.u >> 16) & 1u);
    return (u16)(r >> 16);
}

typedef const __attribute__((address_space(1))) u32* gas1_t;
typedef __attribute__((address_space(3))) u32* las3_t;
#define GLOAD16(g, l) __builtin_amdgcn_global_load_lds((gas1_t)(const void*)(g), (las3_t)(void*)(l), 16, 0, 0)
#define MFMA(a, b, c) __builtin_amdgcn_mfma_f32_16x16x32_bf16((a), (b), (c), 0, 0, 0)
#define CVTPK(dst, lo, hi) asm("v_cvt_pk_bf16_f32 %0, %1, %2" : "=v"(dst) : "v"(lo), "v"(hi))
#define CFENCE() asm volatile("" ::: "memory")
// B-tile swizzle: sigma(row) = (row ^ (row>>2)) & 7.
// Writes (lanes hit rows stride 4): over rows 4i+j, sigma takes all 8 values per
// 8-row sweep -> 2-way (free). Reads (16 consecutive rows): each value 2x -> 2-way.
#define SIGB(r) (((r) ^ ((r) >> 2)) & 7)

// ---------------- small kernels ----------------

__global__ void k_init(int* cnt, float* probsum) {
    int i = threadIdx.x;
    if (i < E_EXP) { cnt[i] = 0; probsum[i] = 0.f; }
}

__global__ __launch_bounds__(256) void k_router(
    const float* __restrict__ x, const float* __restrict__ Wr,
    int* __restrict__ tok_e, float* __restrict__ tok_w,
    int* __restrict__ cnt, float* __restrict__ probsum)
{
    __shared__ float bp[E_EXP];
    __shared__ int   bc[E_EXP];
    const int tid = threadIdx.x;
    if (tid < E_EXP) { bp[tid] = 0.f; bc[tid] = 0; }
    __syncthreads();
    const int wave = tid >> 6, lane = tid & 63;
    const int t = blockIdx.x * 4 + wave;
    const float* xt = x + (size_t)t * D_DIM;
    float a[E_EXP] = {0.f,0.f,0.f,0.f,0.f,0.f,0.f,0.f};
    for (int j = lane; j < D_DIM; j += 64) {
        float xv = xt[j];
        #pragma unroll
        for (int e = 0; e < E_EXP; e++) a[e] = fmaf(xv, Wr[e * D_DIM + j], a[e]);
    }
    #pragma unroll
    for (int e = 0; e < E_EXP; e++) {
        #pragma unroll
        for (int off = 32; off; off >>= 1) a[e] += __shfl_xor(a[e], off, 64);
    }
    if (lane == 0) {
        float mx = a[0];
        #pragma unroll
        for (int e = 1; e < E_EXP; e++) mx = fmaxf(mx, a[e]);
        float p[E_EXP], s = 0.f;
        #pragma unroll
        for (int e = 0; e < E_EXP; e++) { p[e] = expf(a[e] - mx); s += p[e]; }
        float inv = 1.f / s;
        #pragma unroll
        for (int e = 0; e < E_EXP; e++) { p[e] *= inv; atomicAdd(&bp[e], p[e]); }
        int e0 = 0; float v0 = p[0];
        #pragma unroll
        for (int e = 1; e < E_EXP; e++) if (p[e] > v0) { v0 = p[e]; e0 = e; }
        int e1 = -1; float v1 = -1.f;
        #pragma unroll
        for (int e = 0; e < E_EXP; e++) if (e != e0 && p[e] > v1) { v1 = p[e]; e1 = e; }
        float sv = v0 + v1 + 1e-6f;
        tok_e[2*t] = e0; tok_e[2*t+1] = e1;
        tok_w[2*t] = v0 / sv; tok_w[2*t+1] = v1 / sv;
        atomicAdd(&bc[e0], 1); atomicAdd(&bc[e1], 1);
    }
    __syncthreads();
    if (tid < E_EXP) { atomicAdd(&cnt[tid], bc[tid]); atomicAdd(&probsum[tid], bp[tid]); }
}

__global__ void k_prefix(const int* __restrict__ cnt, const float* __restrict__ probsum,
                         int* __restrict__ basep, int* __restrict__ cursor,
                         float* __restrict__ out_lb,
                         int* __restrict__ nt1, int* __restrict__ te1, int* __restrict__ tm1,
                         int* __restrict__ nt2, int* __restrict__ te2, int* __restrict__ tm2)
{
    if (threadIdx.x == 0) {
        int b = 0; float lb = 0.f;
        for (int e = 0; e < E_EXP; e++) {
            basep[e] = b; b += cnt[e];
            lb += ((float)cnt[e] / (8192.f + 1e-6f)) * probsum[e];
        }
        *out_lb = lb * (float)E_EXP;
        int n1 = 0, n2 = 0;
        for (int e = 0; e < E_EXP; e++) {
            for (int m = 0; m < cnt[e]; m += 256) { te1[n1] = e; tm1[n1] = m; n1++; }
            for (int m = 0; m < cnt[e]; m += 128) { te2[n2] = e; tm2[n2] = m; n2++; }
        }
        *nt1 = n1; *nt2 = n2;
    }
    if (threadIdx.x < E_EXP) cursor[threadIdx.x] = 0;
}

__global__ void k_assign(const int* __restrict__ tok_e, const float* __restrict__ tok_w,
                         const int* __restrict__ basep, int* __restrict__ cursor,
                         int* __restrict__ row_token, int* __restrict__ row_slot,
                         float* __restrict__ row_weight)
{
    int t = blockIdx.x * blockDim.x + threadIdx.x;
    if (t >= T_TOK) return;
    #pragma unroll
    for (int k = 0; k < 2; k++) {
        int e = tok_e[2*t + k];
        int pos = basep[e] + atomicAdd(&cursor[e], 1);
        row_token[pos] = t; row_slot[pos] = k; row_weight[pos] = tok_w[2*t + k];
    }
}

__global__ __launch_bounds__(256) void k_cvt_x(const float* __restrict__ in, u16* __restrict__ out) {
    size_t i = ((size_t)blockIdx.x * 256 + threadIdx.x) * 8;
    f32x4 a = *(const f32x4*)(in + i);
    f32x4 b = *(const f32x4*)(in + i + 4);
    bf16x8 o;
    #pragma unroll
    for (int j = 0; j < 4; j++) { o[j] = (short)f2bf(a[j]); o[j + 4] = (short)f2bf(b[j]); }
    *(bf16x8*)(out + i) = o;
}

// ---------------- pass 1: hg = silu(x@Wg) * (x@W1) ----------------
// R13 schedule byte-for-byte (fused fp32-weight transpose-convert; Bh loads before
// COMP(0), cvt between COMPs; single drain+barrier per tile). ONLY change: SIGB.

__global__ __launch_bounds__(512, 2) void k_pass1(
    const u16* __restrict__ xbf,
    const float* __restrict__ W1, const float* __restrict__ Wg,
    const float* __restrict__ b1v, const float* __restrict__ bgv,
    const int* __restrict__ cnt, const int* __restrict__ basep,
    const int* __restrict__ row_token,
    const int* __restrict__ ntp, const int* __restrict__ te, const int* __restrict__ tm,
    u16* __restrict__ hg)
{
    const int ty = blockIdx.y;
    if (ty >= *ntp) return;
    const int e = te[ty];
    const int m0 = tm[ty];
    const int count = cnt[e];
    const int rbase = basep[e];
    const int n0 = blockIdx.x * 128;

    // per buffer (32768 elems = 64KB): A[256x64] @0, Bh[128x64] @16384, Bg @24576
    __shared__ __align__(16) u16 LDS[2 * 32768];

    const int tid = threadIdx.x;
    const int l = tid & 63;
    const int w = tid >> 6;

    // ---- A staging (R11-verified) ----
    const int rb = tid >> 3;
    const int swA = ((tid & 7) ^ ((tid >> 3) & 7)) * 8;
    const u16* sA[4];
    #pragma unroll
    for (int s = 0; s < 4; s++) {
        int g = m0 + rb + s * 64; if (g > count - 1) g = count - 1;
        sA[s] = xbf + (size_t)row_token[rbase + g] * D_DIM + swA;
    }

    // ---- B staging geometry: thread covers 4k x 4n per mat ----
    const int nq = tid & 31;           // n-quad: n = 4*nq .. +3
    const int kq = tid >> 5;           // 0..15: k = 4*kq .. +3 within tile
    const float* pBh = W1 + ((size_t)e * D_DIM + kq * 4) * FF_DIM + n0 + nq * 4;
    const float* pBg = Wg + ((size_t)e * D_DIM + kq * 4) * FF_DIM + n0 + nq * 4;
    const int cW = kq >> 1;            // 16B chunk of this thread's k-quad
    const int offW = (kq & 1) * 4;     // elem offset within chunk
    int wdst[4];
    #pragma unroll
    for (int j = 0; j < 4; j++) {
        const int row = nq * 4 + j;
        wdst[j] = row * 64 + (cW ^ SIGB(row)) * 8 + offW;
    }

    const int wm = w >> 2, wn = w & 3;   // 2M x 4N
    const int fr = l & 15, q = l >> 4;
    const int s7 = fr & 7;

    f32x4 acc_h[8][2], acc_g[8][2];
    const f32x4 z4 = {0.f, 0.f, 0.f, 0.f};
    #pragma unroll
    for (int mf = 0; mf < 8; mf++)
        #pragma unroll
        for (int nf = 0; nf < 2; nf++) { acc_h[mf][nf] = z4; acc_g[mf][nf] = z4; }

    f32x4 vb0, vb1, vb2, vb3;

    #define LOADB1(P, K0) do { \
        const float* p_ = (P) + (size_t)(K0) * FF_DIM; \
        vb0 = *(const f32x4*)(p_); \
        vb1 = *(const f32x4*)(p_ + FF_DIM); \
        vb2 = *(const f32x4*)(p_ + 2 * FF_DIM); \
        vb3 = *(const f32x4*)(p_ + 3 * FF_DIM); \
    } while (0)

    #define CVTW1(BASE) do { \
        _Pragma("unroll") \
        for (int j = 0; j < 4; j++) { \
            u32 lo_, hi_; u32x2 wv_; \
            CVTPK(lo_, vb0[j], vb1[j]); \
            CVTPK(hi_, vb2[j], vb3[j]); \
            wv_.x = lo_; wv_.y = hi_; \
            *(u32x2*)&LDS[(BASE) + wdst[j]] = wv_; \
        } \
    } while (0)

    #define STAGE_A1(B, K0) do { \
        _Pragma("unroll") \
        for (int s = 0; s < 4; s++) \
            GLOAD16(sA[s] + (K0), &LDS[(B) * 32768 + s * 4096 + tid * 8]); \
    } while (0)

    auto COMP = [&](int kk, int ab) {
        const int rsA = ((kk * 4 + q) ^ s7) * 8;
        const int rB0 = wn * 32 + fr, rB1 = wn * 32 + 16 + fr;
        const int cb0 = ((kk * 4 + q) ^ SIGB(rB0)) * 8;
        const int cb1 = ((kk * 4 + q) ^ SIGB(rB1)) * 8;
        bf16x8 bh0 = *(const bf16x8*)&LDS[ab + 16384 + rB0 * 64 + cb0];
        bf16x8 bg0 = *(const bf16x8*)&LDS[ab + 24576 + rB0 * 64 + cb0];
        bf16x8 bh1 = *(const bf16x8*)&LDS[ab + 16384 + rB1 * 64 + cb1];
        bf16x8 bg1 = *(const bf16x8*)&LDS[ab + 24576 + rB1 * 64 + cb1];
        #define LDA1(i) (*(const bf16x8*)&LDS[ab + (wm * 128 + (i) * 16 + fr) * 64 + rsA])
        #define MF4(areg, i) do { \
            __builtin_amdgcn_s_setprio(1); \
            acc_h[i][0] = MFMA(areg, bh0, acc_h[i][0]); \
            acc_h[i][1] = MFMA(areg, bh1, acc_h[i][1]); \
            acc_g[i][0] = MFMA(areg, bg0, acc_g[i][0]); \
            acc_g[i][1] = MFMA(areg, bg1, acc_g[i][1]); \
            __builtin_amdgcn_s_setprio(0); } while (0)
        bf16x8 aA = LDA1(0);
        bf16x8 aB = LDA1(1);
        bf16x8 aC;
        aC = LDA1(2); MF4(aA, 0);
        aA = LDA1(3); MF4(aB, 1);
        aB = LDA1(4); MF4(aC, 2);
        aC = LDA1(5); MF4(aA, 3);
        aA = LDA1(6); MF4(aB, 4);
        aB = LDA1(7); MF4(aC, 5);
        MF4(aA, 6);
        MF4(aB, 7);
        #undef LDA1
        #undef MF4
    };

    const int NT = D_DIM / 64;   // 16
    // prologue: tile 0 -> buf 0
    LOADB1(pBh, 0);
    CVTW1(0 + 16384);
    STAGE_A1(0, 0);
    LOADB1(pBg, 0);
    CVTW1(0 + 24576);
    asm volatile("s_waitcnt vmcnt(0) lgkmcnt(0)" ::: "memory");
    __builtin_amdgcn_s_barrier();
    CFENCE();

    int b = 0;
    #pragma unroll 1
    for (int t = 0; t < NT; ++t) {
        const int ab = b * 32768;
        const int nboff = (b ^ 1) * 32768;
        const int kN = (t + 1 < NT ? t + 1 : NT - 1) * 64;
        LOADB1(pBh, kN);
        COMP(0, ab);
        CVTW1(nboff + 16384);
        STAGE_A1(b ^ 1, kN);
        LOADB1(pBg, kN);
        COMP(1, ab);
        CVTW1(nboff + 24576);
        asm volatile("s_waitcnt vmcnt(0) lgkmcnt(0)" ::: "memory");
        __builtin_amdgcn_s_barrier();
        CFENCE();
        b ^= 1;
    }
    asm volatile("s_waitcnt vmcnt(0)" ::: "memory");
    #undef LOADB1
    #undef CVTW1
    #undef STAGE_A1

    const float* b1p = b1v + (size_t)e * FF_DIM + n0;
    const float* bgp = bgv + (size_t)e * FF_DIM + n0;
    #pragma unroll
    for (int mf = 0; mf < 8; mf++) {
        const int rl = wm * 128 + mf * 16 + q * 4;
        #pragma unroll
        for (int r = 0; r < 4; r++) {
            const int g = m0 + rl + r;
            if (g < count) {
                u16* orow = hg + (size_t)(rbase + g) * FF_DIM + n0;
                #pragma unroll
                for (int nf = 0; nf < 2; nf++) {
                    const int col = wn * 32 + nf * 16 + fr;
                    float hv = acc_h[mf][nf][r] + b1p[col];
                    float gv = acc_g[mf][nf][r] + bgp[col];
                    float sig = 1.f / (1.f + expf(-gv));
                    orow[col] = f2bf(gv * sig * hv);
                }
            }
        }
    }
}

// ---------------- pass 2: contrib[slot] = w * (hg @ W2 + b2) ----------------
// R13 schedule byte-for-byte. ONLY change: SIGB.

__global__ __launch_bounds__(256, 2) void k_pass2(
    const u16* __restrict__ hg,
    const float* __restrict__ W2, const float* __restrict__ b2v,
    const int* __restrict__ cnt, const int* __restrict__ basep,
    const int* __restrict__ row_token, const int* __restrict__ row_slot,
    const float* __restrict__ row_weight,
    const int* __restrict__ ntp, const int* __restrict__ te, const int* __restrict__ tm,
    float* __restrict__ contrib)
{
    const int ty = blockIdx.y;
    if (ty >= *ntp) return;
    const int e = te[ty];
    const int m0 = tm[ty];
    const int count = cnt[e];
    const int rbase = basep[e];
    const int n0 = blockIdx.x * 128;

    // per buffer (16384 elems = 32KB): A[128x64] @0, B[128x64] @8192
    __shared__ __align__(16) u16 LDS[2 * 16384];

    const int tid = threadIdx.x;
    const int l = tid & 63;
    const int w = tid >> 6;

    // A staging
    const int rb = tid >> 3;
    const int swA = ((tid & 7) ^ ((tid >> 3) & 7)) * 8;
    const u16* sA[4];
    #pragma unroll
    for (int s = 0; s < 4; s++) {
        int g = m0 + rb + s * 32; if (g > count - 1) g = count - 1;
        sA[s] = hg + (size_t)(rbase + g) * FF_DIM + swA;
    }

    // B staging: thread covers 8k x 4n (two 4k batches)
    const int nq = tid & 31;           // n = 4*nq .. +3
    const int koct = tid >> 5;         // 0..7: k = 8*koct .. +7
    const float* pB = W2 + ((size_t)e * FF_DIM + koct * 8) * D_DIM + n0 + nq * 4;
    int wdst[4];
    #pragma unroll
    for (int j = 0; j < 4; j++) {
        const int row = nq * 4 + j;
        wdst[j] = row * 64 + (koct ^ SIGB(row)) * 8;
    }

    const int wm = w >> 1, wn = w & 1;   // 2M x 2N
    const int fr = l & 15, q = l >> 4;
    const int s7 = fr & 7;

    f32x4 acc[4][4];
    const f32x4 z4 = {0.f, 0.f, 0.f, 0.f};
    #pragma unroll
    for (int mf = 0; mf < 4; mf++)
        #pragma unroll
        for (int nf = 0; nf < 4; nf++) acc[mf][nf] = z4;

    f32x4 vb0, vb1, vb2, vb3;

    #define LOADB2(K0, BT) do { \
        const float* p_ = pB + (size_t)((K0) + (BT) * 4) * D_DIM; \
        vb0 = *(const f32x4*)(p_); \
        vb1 = *(const f32x4*)(p_ + D_DIM); \
        vb2 = *(const f32x4*)(p_ + 2 * D_DIM); \
        vb3 = *(const f32x4*)(p_ + 3 * D_DIM); \
    } while (0)

    #define CVTW2(BASE, BT) do { \
        _Pragma("unroll") \
        for (int j = 0; j < 4; j++) { \
            u32 lo_, hi_; u32x2 wv_; \
            CVTPK(lo_, vb0[j], vb1[j]); \
            CVTPK(hi_, vb2[j], vb3[j]); \
            wv_.x = lo_; wv_.y = hi_; \
            *(u32x2*)&LDS[(BASE) + wdst[j] + (BT) * 4] = wv_; \
        } \
    } while (0)

    #define STAGE_A2(B, K0) do { \
        _Pragma("unroll") \
        for (int s = 0; s < 4; s++) \
            GLOAD16(sA[s] + (K0), &LDS[(B) * 16384 + s * 2048 + tid * 8]); \
    } while (0)

    auto COMP = [&](int kk, int ab) {
        const int rsA = ((kk * 4 + q) ^ s7) * 8;
        bf16x8 a0, a1, a2, a3, bb0, bb1, bb2, bb3;
        {
            const int r0 = wn * 64 + fr, r1 = wn * 64 + 16 + fr;
            const int r2 = wn * 64 + 32 + fr, r3 = wn * 64 + 48 + fr;
            bb0 = *(const bf16x8*)&LDS[ab + 8192 + r0 * 64 + (((kk * 4 + q) ^ SIGB(r0)) * 8)];
            bb1 = *(const bf16x8*)&LDS[ab + 8192 + r1 * 64 + (((kk * 4 + q) ^ SIGB(r1)) * 8)];
            bb2 = *(const bf16x8*)&LDS[ab + 8192 + r2 * 64 + (((kk * 4 + q) ^ SIGB(r2)) * 8)];
            bb3 = *(const bf16x8*)&LDS[ab + 8192 + r3 * 64 + (((kk * 4 + q) ^ SIGB(r3)) * 8)];
        }
        a0 = *(const bf16x8*)&LDS[ab + (wm * 64 + 0 * 16 + fr) * 64 + rsA];
        a1 = *(const bf16x8*)&LDS[ab + (wm * 64 + 1 * 16 + fr) * 64 + rsA];
        a2 = *(const bf16x8*)&LDS[ab + (wm * 64 + 2 * 16 + fr) * 64 + rsA];
        a3 = *(const bf16x8*)&LDS[ab + (wm * 64 + 3 * 16 + fr) * 64 + rsA];
        __builtin_amdgcn_s_setprio(1);
        acc[0][0] = MFMA(a0, bb0, acc[0][0]); acc[0][1] = MFMA(a0, bb1, acc[0][1]);
        acc[0][2] = MFMA(a0, bb2, acc[0][2]); acc[0][3] = MFMA(a0, bb3, acc[0][3]);
        acc[1][0] = MFMA(a1, bb0, acc[1][0]); acc[1][1] = MFMA(a1, bb1, acc[1][1]);
        acc[1][2] = MFMA(a1, bb2, acc[1][2]); acc[1][3] = MFMA(a1, bb3, acc[1][3]);
        acc[2][0] = MFMA(a2, bb0, acc[2][0]); acc[2][1] = MFMA(a2, bb1, acc[2][1]);
        acc[2][2] = MFMA(a2, bb2, acc[2][2]); acc[2][3] = MFMA(a2, bb3, acc[2][3]);
        acc[3][0] = MFMA(a3, bb0, acc[3][0]); acc[3][1] = MFMA(a3, bb1, acc[3][1]);
        acc[3][2] = MFMA(a3, bb2, acc[3][2]); acc[3][3] = MFMA(a3, bb3, acc[3][3]);
        __builtin_amdgcn_s_setprio(0);
    };

    const int NT = FF_DIM / 64;   // 64
    LOADB2(0, 0);
    CVTW2(8192, 0);
    STAGE_A2(0, 0);
    LOADB2(0, 1);
    CVTW2(8192, 1);
    asm volatile("s_waitcnt vmcnt(0) lgkmcnt(0)" ::: "memory");
    __builtin_amdgcn_s_barrier();
    CFENCE();

    int b = 0;
    #pragma unroll 1
    for (int t = 0; t < NT; ++t) {
        const int ab = b * 16384;
        const int nboff = (b ^ 1) * 16384;
        const int kN = (t + 1 < NT ? t + 1 : NT - 1) * 64;
        LOADB2(kN, 0);
        COMP(0, ab);
        CVTW2(nboff + 8192, 0);
        STAGE_A2(b ^ 1, kN);
        LOADB2(kN, 1);
        COMP(1, ab);
        CVTW2(nboff + 8192, 1);
        asm volatile("s_waitcnt vmcnt(0) lgkmcnt(0)" ::: "memory");
        __builtin_amdgcn_s_barrier();
        CFENCE();
        b ^= 1;
    }
    asm volatile("s_waitcnt vmcnt(0)" ::: "memory");
    #undef LOADB2
    #undef CVTW2
    #undef STAGE_A2

    const float* b2p = b2v + (size_t)e * D_DIM + n0;
    #pragma unroll
    for (int mf = 0; mf < 4; mf++) {
        const int rl = wm * 64 + mf * 16 + q * 4;
        #pragma unroll
        for (int r = 0; r < 4; r++) {
            const int g = m0 + rl + r;
            if (g < count) {
                const int token = row_token[rbase + g];
                const int slot  = row_slot[rbase + g];
                const float wgt_ = row_weight[rbase + g];
                float* orow = contrib + ((size_t)slot * T_TOK + token) * D_DIM + n0;
                #pragma unroll
                for (int nf = 0; nf < 4; nf++) {
                    const int col = wn * 64 + nf * 16 + fr;
                    orow[col] = wgt_ * (acc[mf][nf][r] + b2p[col]);
                }
            }
        }
    }
}

__global__ void k_combine(const float* __restrict__ contrib, float* __restrict__ out) {
    int i = blockIdx.x * blockDim.x + threadIdx.x;
    const f32x4* c0 = (const f32x4*)contrib;
    const f32x4* c1 = c0 + ((size_t)T_TOK * D_DIM / 4);
    f32x4* o = (f32x4*)out;
    o[i] = c0[i] + c1[i];
}

// ---------------- launch ----------------

extern "C" void kernel_launch(void* const* d_in, const int* in_sizes, int n_in,
                              void* d_out, int out_size, void* d_ws, size_t ws_size,
                              hipStream_t stream)
{
    (void)in_sizes; (void)n_in; (void)out_size; (void)ws_size;
    const float* x  = (const float*)d_in[0];
    const float* Wr = (const float*)d_in[1];
    const float* W1 = (const float*)d_in[2];
    const float* b1 = (const float*)d_in[3];
    const float* Wg = (const float*)d_in[4];
    const float* bg = (const float*)d_in[5];
    const float* W2 = (const float*)d_in[6];
    const float* b2 = (const float*)d_in[7];
    float* out = (float*)d_out;

    char* ws = (char*)d_ws;
    u16* xbf = (u16*)ws;             ws += (size_t)T_TOK * D_DIM * sizeof(u16);
    u16* hg = (u16*)ws;              ws += (size_t)NROWS * FF_DIM * sizeof(u16);
    float* contrib = (float*)ws;     ws += (size_t)2 * T_TOK * D_DIM * sizeof(float);
    int* tok_e = (int*)ws;           ws += (size_t)T_TOK * 2 * sizeof(int);
    float* tok_w = (float*)ws;       ws += (size_t)T_TOK * 2 * sizeof(float);
    int* row_token = (int*)ws;       ws += (size_t)NROWS * sizeof(int);
    int* row_slot = (int*)ws;        ws += (size_t)NROWS * sizeof(int);
    float* row_weight = (float*)ws;  ws += (size_t)NROWS * sizeof(float);
    int* cnt = (int*)ws;             ws += 8 * sizeof(int);
    int* basep = (int*)ws;           ws += 8 * sizeof(int);
    int* cursor = (int*)ws;          ws += 8 * sizeof(int);
    float* probsum = (float*)ws;     ws += 8 * sizeof(float);
    int* nt1 = (int*)ws;             ws += sizeof(int);
    int* nt2 = (int*)ws;             ws += sizeof(int);
    int* te1 = (int*)ws;             ws += MAXT1 * sizeof(int);
    int* tm1 = (int*)ws;             ws += MAXT1 * sizeof(int);
    int* te2 = (int*)ws;             ws += MAXT2 * sizeof(int);
    int* tm2 = (int*)ws;             ws += MAXT2 * sizeof(int);

    k_init<<<1, 64, 0, stream>>>(cnt, probsum);
    k_cvt_x<<<(T_TOK * D_DIM / 8) / 256, 256, 0, stream>>>(x, xbf);
    k_router<<<T_TOK / 4, 256, 0, stream>>>(x, Wr, tok_e, tok_w, cnt, probsum);
    k_prefix<<<1, 64, 0, stream>>>(cnt, probsum, basep, cursor, out + (size_t)T_TOK * D_DIM,
                                   nt1, te1, tm1, nt2, te2, tm2);
    k_assign<<<T_TOK / 256, 256, 0, stream>>>(tok_e, tok_w, basep, cursor, row_token, row_slot, row_weight);
    k_pass1<<<dim3(FF_DIM / 128, MAXT1), 512, 0, stream>>>(xbf, W1, Wg, b1, bg, cnt, basep, row_token,
                                                           nt1, te1, tm1, hg);
    k_pass2<<<dim3(D_DIM / 128, MAXT2), 256, 0, stream>>>(hg, W2, b2, cnt, basep, row_token, row_slot, row_weight,
                                                          nt2, te2, tm2, contrib);
    k_combine<<<(T_TOK * D_DIM / 4) / 256, 256, 0, stream>>>(contrib, out);
}

// Round 16
// 500.832 us; speedup vs baseline: 1.0322x; 1.0026x over previous
//
#include <hip/hip_runtime.h>
#include <hip/hip_bf16.h>
#include <math.h>

#define T_TOK 4096
#define D_DIM 1024
#define E_EXP 8
#define FF_DIM 4096
#define NROWS (T_TOK * 2)
#define MAXT1 40   // max m-tiles (BM=256): 8192/256 + 8
#define MAXT2 72   // max m-tiles (BM=128): 8192/128 + 8 (table still built; unused)

typedef unsigned short u16;
typedef unsigned int u32;
typedef __attribute__((ext_vector_type(8))) short bf16x8;
typedef __attribute__((ext_vector_type(4))) float f32x4;
typedef __attribute__((ext_vector_type(2))) unsigned int u32x2;

__device__ __forceinline__ u16 f2bf(float f) {
    union { float f; unsigned u; } v; v.f = f;
    unsigned r = v.u + 0x7FFFu + ((v.u >> 16) & 1u);
    return (u16)(r >> 16);
}

typedef const __attribute__((address_space(1))) u32* gas1_t;
typedef __attribute__((address_space(3))) u32* las3_t;
#define GLOAD16(g, l) __builtin_amdgcn_global_load_lds((gas1_t)(const void*)(g), (las3_t)(void*)(l), 16, 0, 0)
#define MFMA(a, b, c) __builtin_amdgcn_mfma_f32_16x16x32_bf16((a), (b), (c), 0, 0, 0)
#define CVTPK(dst, lo, hi) asm("v_cvt_pk_bf16_f32 %0, %1, %2" : "=v"(dst) : "v"(lo), "v"(hi))
#define CFENCE() asm volatile("" ::: "memory")
// B-tile swizzle: sigma(row) = (row ^ (row>>2)) & 7.
// Writes (lanes hit rows stride 4): all 8 values per 8-row sweep -> 2-way (free).
// Reads (16 consecutive rows): each value 2x -> 2-way (free).
#define SIGB(r) (((r) ^ ((r) >> 2)) & 7)

// ---------------- small kernels ----------------

__global__ void k_init(int* cnt, float* probsum) {
    int i = threadIdx.x;
    if (i < E_EXP) { cnt[i] = 0; probsum[i] = 0.f; }
}

__global__ __launch_bounds__(256) void k_router(
    const float* __restrict__ x, const float* __restrict__ Wr,
    int* __restrict__ tok_e, float* __restrict__ tok_w,
    int* __restrict__ cnt, float* __restrict__ probsum)
{
    __shared__ float bp[E_EXP];
    __shared__ int   bc[E_EXP];
    const int tid = threadIdx.x;
    if (tid < E_EXP) { bp[tid] = 0.f; bc[tid] = 0; }
    __syncthreads();
    const int wave = tid >> 6, lane = tid & 63;
    const int t = blockIdx.x * 4 + wave;
    const float* xt = x + (size_t)t * D_DIM;
    float a[E_EXP] = {0.f,0.f,0.f,0.f,0.f,0.f,0.f,0.f};
    for (int j = lane; j < D_DIM; j += 64) {
        float xv = xt[j];
        #pragma unroll
        for (int e = 0; e < E_EXP; e++) a[e] = fmaf(xv, Wr[e * D_DIM + j], a[e]);
    }
    #pragma unroll
    for (int e = 0; e < E_EXP; e++) {
        #pragma unroll
        for (int off = 32; off; off >>= 1) a[e] += __shfl_xor(a[e], off, 64);
    }
    if (lane == 0) {
        float mx = a[0];
        #pragma unroll
        for (int e = 1; e < E_EXP; e++) mx = fmaxf(mx, a[e]);
        float p[E_EXP], s = 0.f;
        #pragma unroll
        for (int e = 0; e < E_EXP; e++) { p[e] = expf(a[e] - mx); s += p[e]; }
        float inv = 1.f / s;
        #pragma unroll
        for (int e = 0; e < E_EXP; e++) { p[e] *= inv; atomicAdd(&bp[e], p[e]); }
        int e0 = 0; float v0 = p[0];
        #pragma unroll
        for (int e = 1; e < E_EXP; e++) if (p[e] > v0) { v0 = p[e]; e0 = e; }
        int e1 = -1; float v1 = -1.f;
        #pragma unroll
        for (int e = 0; e < E_EXP; e++) if (e != e0 && p[e] > v1) { v1 = p[e]; e1 = e; }
        float sv = v0 + v1 + 1e-6f;
        tok_e[2*t] = e0; tok_e[2*t+1] = e1;
        tok_w[2*t] = v0 / sv; tok_w[2*t+1] = v1 / sv;
        atomicAdd(&bc[e0], 1); atomicAdd(&bc[e1], 1);
    }
    __syncthreads();
    if (tid < E_EXP) { atomicAdd(&cnt[tid], bc[tid]); atomicAdd(&probsum[tid], bp[tid]); }
}

__global__ void k_prefix(const int* __restrict__ cnt, const float* __restrict__ probsum,
                         int* __restrict__ basep, int* __restrict__ cursor,
                         float* __restrict__ out_lb,
                         int* __restrict__ nt1, int* __restrict__ te1, int* __restrict__ tm1)
{
    if (threadIdx.x == 0) {
        int b = 0; float lb = 0.f;
        for (int e = 0; e < E_EXP; e++) {
            basep[e] = b; b += cnt[e];
            lb += ((float)cnt[e] / (8192.f + 1e-6f)) * probsum[e];
        }
        *out_lb = lb * (float)E_EXP;
        int n1 = 0;
        for (int e = 0; e < E_EXP; e++)
            for (int m = 0; m < cnt[e]; m += 256) { te1[n1] = e; tm1[n1] = m; n1++; }
        *nt1 = n1;
    }
    if (threadIdx.x < E_EXP) cursor[threadIdx.x] = 0;
}

__global__ void k_assign(const int* __restrict__ tok_e, const float* __restrict__ tok_w,
                         const int* __restrict__ basep, int* __restrict__ cursor,
                         int* __restrict__ row_token, int* __restrict__ row_slot,
                         float* __restrict__ row_weight)
{
    int t = blockIdx.x * blockDim.x + threadIdx.x;
    if (t >= T_TOK) return;
    #pragma unroll
    for (int k = 0; k < 2; k++) {
        int e = tok_e[2*t + k];
        int pos = basep[e] + atomicAdd(&cursor[e], 1);
        row_token[pos] = t; row_slot[pos] = k; row_weight[pos] = tok_w[2*t + k];
    }
}

__global__ __launch_bounds__(256) void k_cvt_x(const float* __restrict__ in, u16* __restrict__ out) {
    size_t i = ((size_t)blockIdx.x * 256 + threadIdx.x) * 8;
    f32x4 a = *(const f32x4*)(in + i);
    f32x4 b = *(const f32x4*)(in + i + 4);
    bf16x8 o;
    #pragma unroll
    for (int j = 0; j < 4; j++) { o[j] = (short)f2bf(a[j]); o[j + 4] = (short)f2bf(b[j]); }
    *(bf16x8*)(out + i) = o;
}

// ---------------- pass 1: hg = silu(x@Wg) * (x@W1) ----------------
// Unchanged from R15 (fused fp32-weight transpose-convert, SIGB swizzle).

__global__ __launch_bounds__(512, 2) void k_pass1(
    const u16* __restrict__ xbf,
    const float* __restrict__ W1, const float* __restrict__ Wg,
    const float* __restrict__ b1v, const float* __restrict__ bgv,
    const int* __restrict__ cnt, const int* __restrict__ basep,
    const int* __restrict__ row_token,
    const int* __restrict__ ntp, const int* __restrict__ te, const int* __restrict__ tm,
    u16* __restrict__ hg)
{
    const int ty = blockIdx.y;
    if (ty >= *ntp) return;
    const int e = te[ty];
    const int m0 = tm[ty];
    const int count = cnt[e];
    const int rbase = basep[e];
    const int n0 = blockIdx.x * 128;

    // per buffer (32768 elems = 64KB): A[256x64] @0, Bh[128x64] @16384, Bg @24576
    __shared__ __align__(16) u16 LDS[2 * 32768];

    const int tid = threadIdx.x;
    const int l = tid & 63;
    const int w = tid >> 6;

    const int rb = tid >> 3;
    const int swA = ((tid & 7) ^ ((tid >> 3) & 7)) * 8;
    const u16* sA[4];
    #pragma unroll
    for (int s = 0; s < 4; s++) {
        int g = m0 + rb + s * 64; if (g > count - 1) g = count - 1;
        sA[s] = xbf + (size_t)row_token[rbase + g] * D_DIM + swA;
    }

    const int nq = tid & 31;
    const int kq = tid >> 5;
    const float* pBh = W1 + ((size_t)e * D_DIM + kq * 4) * FF_DIM + n0 + nq * 4;
    const float* pBg = Wg + ((size_t)e * D_DIM + kq * 4) * FF_DIM + n0 + nq * 4;
    const int cW = kq >> 1;
    const int offW = (kq & 1) * 4;
    int wdst[4];
    #pragma unroll
    for (int j = 0; j < 4; j++) {
        const int row = nq * 4 + j;
        wdst[j] = row * 64 + (cW ^ SIGB(row)) * 8 + offW;
    }

    const int wm = w >> 2, wn = w & 3;
    const int fr = l & 15, q = l >> 4;
    const int s7 = fr & 7;

    f32x4 acc_h[8][2], acc_g[8][2];
    const f32x4 z4 = {0.f, 0.f, 0.f, 0.f};
    #pragma unroll
    for (int mf = 0; mf < 8; mf++)
        #pragma unroll
        for (int nf = 0; nf < 2; nf++) { acc_h[mf][nf] = z4; acc_g[mf][nf] = z4; }

    f32x4 vb0, vb1, vb2, vb3;

    #define LOADB1(P, K0) do { \
        const float* p_ = (P) + (size_t)(K0) * FF_DIM; \
        vb0 = *(const f32x4*)(p_); \
        vb1 = *(const f32x4*)(p_ + FF_DIM); \
        vb2 = *(const f32x4*)(p_ + 2 * FF_DIM); \
        vb3 = *(const f32x4*)(p_ + 3 * FF_DIM); \
    } while (0)

    #define CVTW1(BASE) do { \
        _Pragma("unroll") \
        for (int j = 0; j < 4; j++) { \
            u32 lo_, hi_; u32x2 wv_; \
            CVTPK(lo_, vb0[j], vb1[j]); \
            CVTPK(hi_, vb2[j], vb3[j]); \
            wv_.x = lo_; wv_.y = hi_; \
            *(u32x2*)&LDS[(BASE) + wdst[j]] = wv_; \
        } \
    } while (0)

    #define STAGE_A1(B, K0) do { \
        _Pragma("unroll") \
        for (int s = 0; s < 4; s++) \
            GLOAD16(sA[s] + (K0), &LDS[(B) * 32768 + s * 4096 + tid * 8]); \
    } while (0)

    auto COMP = [&](int kk, int ab) {
        const int rsA = ((kk * 4 + q) ^ s7) * 8;
        const int rB0 = wn * 32 + fr, rB1 = wn * 32 + 16 + fr;
        const int cb0 = ((kk * 4 + q) ^ SIGB(rB0)) * 8;
        const int cb1 = ((kk * 4 + q) ^ SIGB(rB1)) * 8;
        bf16x8 bh0 = *(const bf16x8*)&LDS[ab + 16384 + rB0 * 64 + cb0];
        bf16x8 bg0 = *(const bf16x8*)&LDS[ab + 24576 + rB0 * 64 + cb0];
        bf16x8 bh1 = *(const bf16x8*)&LDS[ab + 16384 + rB1 * 64 + cb1];
        bf16x8 bg1 = *(const bf16x8*)&LDS[ab + 24576 + rB1 * 64 + cb1];
        #define LDA1(i) (*(const bf16x8*)&LDS[ab + (wm * 128 + (i) * 16 + fr) * 64 + rsA])
        #define MF4(areg, i) do { \
            __builtin_amdgcn_s_setprio(1); \
            acc_h[i][0] = MFMA(areg, bh0, acc_h[i][0]); \
            acc_h[i][1] = MFMA(areg, bh1, acc_h[i][1]); \
            acc_g[i][0] = MFMA(areg, bg0, acc_g[i][0]); \
            acc_g[i][1] = MFMA(areg, bg1, acc_g[i][1]); \
            __builtin_amdgcn_s_setprio(0); } while (0)
        bf16x8 aA = LDA1(0);
        bf16x8 aB = LDA1(1);
        bf16x8 aC;
        aC = LDA1(2); MF4(aA, 0);
        aA = LDA1(3); MF4(aB, 1);
        aB = LDA1(4); MF4(aC, 2);
        aC = LDA1(5); MF4(aA, 3);
        aA = LDA1(6); MF4(aB, 4);
        aB = LDA1(7); MF4(aC, 5);
        MF4(aA, 6);
        MF4(aB, 7);
        #undef LDA1
        #undef MF4
    };

    const int NT = D_DIM / 64;   // 16
    LOADB1(pBh, 0);
    CVTW1(0 + 16384);
    STAGE_A1(0, 0);
    LOADB1(pBg, 0);
    CVTW1(0 + 24576);
    asm volatile("s_waitcnt vmcnt(0) lgkmcnt(0)" ::: "memory");
    __builtin_amdgcn_s_barrier();
    CFENCE();

    int b = 0;
    #pragma unroll 1
    for (int t = 0; t < NT; ++t) {
        const int ab = b * 32768;
        const int nboff = (b ^ 1) * 32768;
        const int kN = (t + 1 < NT ? t + 1 : NT - 1) * 64;
        LOADB1(pBh, kN);
        COMP(0, ab);
        CVTW1(nboff + 16384);
        STAGE_A1(b ^ 1, kN);
        LOADB1(pBg, kN);
        COMP(1, ab);
        CVTW1(nboff + 24576);
        asm volatile("s_waitcnt vmcnt(0) lgkmcnt(0)" ::: "memory");
        __builtin_amdgcn_s_barrier();
        CFENCE();
        b ^= 1;
    }
    asm volatile("s_waitcnt vmcnt(0)" ::: "memory");
    #undef LOADB1
    #undef CVTW1
    #undef STAGE_A1

    const float* b1p = b1v + (size_t)e * FF_DIM + n0;
    const float* bgp = bgv + (size_t)e * FF_DIM + n0;
    #pragma unroll
    for (int mf = 0; mf < 8; mf++) {
        const int rl = wm * 128 + mf * 16 + q * 4;
        #pragma unroll
        for (int r = 0; r < 4; r++) {
            const int g = m0 + rl + r;
            if (g < count) {
                u16* orow = hg + (size_t)(rbase + g) * FF_DIM + n0;
                #pragma unroll
                for (int nf = 0; nf < 2; nf++) {
                    const int col = wn * 32 + nf * 16 + fr;
                    float hv = acc_h[mf][nf][r] + b1p[col];
                    float gv = acc_g[mf][nf][r] + bgp[col];
                    float sig = 1.f / (1.f + expf(-gv));
                    orow[col] = f2bf(gv * sig * hv);
                }
            }
        }
    }
}

// ---------------- pass 2: contrib[slot] = w * (hg @ W2 + b2) ----------------
// STRUCTURAL CLONE of fused pass1 minus the G-mat: BM=256 BN=128 BK=64, 8 waves
// (per-wave 128x32, acc 8x2), LDS 2 x 48KB (A 32KB @0, B 16KB @16384).
// W2 fp32 from [E][FF][D] fused transpose-convert (SIGB); A = hg via gload_lds.
// Grid: x = m-tile (BM=256 table, 4/expert), y = n-tile; consecutive blocks
// share the W2 panel (L2 locality); W2 re-read 4x (vs 8x at BM=128).

__global__ __launch_bounds__(512, 2) void k_pass2(
    const u16* __restrict__ hg,
    const float* __restrict__ W2, const float* __restrict__ b2v,
    const int* __restrict__ cnt, const int* __restrict__ basep,
    const int* __restrict__ row_token, const int* __restrict__ row_slot,
    const float* __restrict__ row_weight,
    const int* __restrict__ ntp, const int* __restrict__ te, const int* __restrict__ tm,
    float* __restrict__ contrib)
{
    const int ty = blockIdx.x;
    if (ty >= *ntp) return;
    const int e = te[ty];
    const int m0 = tm[ty];
    const int count = cnt[e];
    const int rbase = basep[e];
    const int n0 = blockIdx.y * 128;

    // per buffer (24576 elems = 48KB): A[256x64] @0 (16384 elems), B[128x64] @16384 (8192)
    __shared__ __align__(16) u16 LDS[2 * 24576];

    const int tid = threadIdx.x;
    const int l = tid & 63;
    const int w = tid >> 6;

    // A staging: rows direct from gathered hg
    const int rb = tid >> 3;
    const int swA = ((tid & 7) ^ ((tid >> 3) & 7)) * 8;
    const u16* sA[4];
    #pragma unroll
    for (int s = 0; s < 4; s++) {
        int g = m0 + rb + s * 64; if (g > count - 1) g = count - 1;
        sA[s] = hg + (size_t)(rbase + g) * FF_DIM + swA;
    }

    // B staging geometry (thread covers 4k x 4n): B[n][k] = W2[e][k][n]
    const int nq = tid & 31;           // n = 4*nq .. +3
    const int kq = tid >> 5;           // 0..15: k = 4*kq .. +3 within tile
    const float* pB = W2 + ((size_t)e * FF_DIM + kq * 4) * D_DIM + n0 + nq * 4;
    const int cW = kq >> 1;
    const int offW = (kq & 1) * 4;
    int wdst[4];
    #pragma unroll
    for (int j = 0; j < 4; j++) {
        const int row = nq * 4 + j;
        wdst[j] = 16384 + row * 64 + (cW ^ SIGB(row)) * 8 + offW;
    }

    const int wm = w >> 2, wn = w & 3;   // 2M x 4N, per-wave 128x32
    const int fr = l & 15, q = l >> 4;
    const int s7 = fr & 7;

    f32x4 acc[8][2];
    const f32x4 z4 = {0.f, 0.f, 0.f, 0.f};
    #pragma unroll
    for (int mf = 0; mf < 8; mf++)
        #pragma unroll
        for (int nf = 0; nf < 2; nf++) acc[mf][nf] = z4;

    f32x4 vb0, vb1, vb2, vb3;

    #define LOADB2(K0) do { \
        const float* p_ = pB + (size_t)(K0) * D_DIM; \
        vb0 = *(const f32x4*)(p_); \
        vb1 = *(const f32x4*)(p_ + D_DIM); \
        vb2 = *(const f32x4*)(p_ + 2 * D_DIM); \
        vb3 = *(const f32x4*)(p_ + 3 * D_DIM); \
    } while (0)

    #define CVTW2(BASE) do { \
        _Pragma("unroll") \
        for (int j = 0; j < 4; j++) { \
            u32 lo_, hi_; u32x2 wv_; \
            CVTPK(lo_, vb0[j], vb1[j]); \
            CVTPK(hi_, vb2[j], vb3[j]); \
            wv_.x = lo_; wv_.y = hi_; \
            *(u32x2*)&LDS[(BASE) + wdst[j]] = wv_; \
        } \
    } while (0)

    #define STAGE_A2(B, K0) do { \
        _Pragma("unroll") \
        for (int s = 0; s < 4; s++) \
            GLOAD16(sA[s] + (K0), &LDS[(B) * 24576 + s * 4096 + tid * 8]); \
    } while (0)

    auto COMP = [&](int kk, int ab) {
        const int rsA = ((kk * 4 + q) ^ s7) * 8;
        const int rB0 = wn * 32 + fr, rB1 = wn * 32 + 16 + fr;
        const int cb0 = ((kk * 4 + q) ^ SIGB(rB0)) * 8;
        const int cb1 = ((kk * 4 + q) ^ SIGB(rB1)) * 8;
        bf16x8 bb0 = *(const bf16x8*)&LDS[ab + 16384 + rB0 * 64 + cb0];
        bf16x8 bb1 = *(const bf16x8*)&LDS[ab + 16384 + rB1 * 64 + cb1];
        #define LDA2(i) (*(const bf16x8*)&LDS[ab + (wm * 128 + (i) * 16 + fr) * 64 + rsA])
        #define MF2(areg, i) do { \
            __builtin_amdgcn_s_setprio(1); \
            acc[i][0] = MFMA(areg, bb0, acc[i][0]); \
            acc[i][1] = MFMA(areg, bb1, acc[i][1]); \
            __builtin_amdgcn_s_setprio(0); } while (0)
        bf16x8 aA = LDA2(0);
        bf16x8 aB = LDA2(1);
        bf16x8 aC;
        aC = LDA2(2); MF2(aA, 0);
        aA = LDA2(3); MF2(aB, 1);
        aB = LDA2(4); MF2(aC, 2);
        aC = LDA2(5); MF2(aA, 3);
        aA = LDA2(6); MF2(aB, 4);
        aB = LDA2(7); MF2(aC, 5);
        MF2(aA, 6);
        MF2(aB, 7);
        #undef LDA2
        #undef MF2
    };

    const int NT = FF_DIM / 64;   // 64
    LOADB2(0);
    CVTW2(0);
    STAGE_A2(0, 0);
    asm volatile("s_waitcnt vmcnt(0) lgkmcnt(0)" ::: "memory");
    __builtin_amdgcn_s_barrier();
    CFENCE();

    int b = 0;
    #pragma unroll 1
    for (int t = 0; t < NT; ++t) {
        const int ab = b * 24576;
        const int nboff = (b ^ 1) * 24576;
        const int kN = (t + 1 < NT ? t + 1 : NT - 1) * 64;
        LOADB2(kN);
        COMP(0, ab);
        CVTW2(nboff);
        STAGE_A2(b ^ 1, kN);
        COMP(1, ab);
        asm volatile("s_waitcnt vmcnt(0) lgkmcnt(0)" ::: "memory");
        __builtin_amdgcn_s_barrier();
        CFENCE();
        b ^= 1;
    }
    asm volatile("s_waitcnt vmcnt(0)" ::: "memory");
    #undef LOADB2
    #undef CVTW2
    #undef STAGE_A2

    const float* b2p = b2v + (size_t)e * D_DIM + n0;
    #pragma unroll
    for (int mf = 0; mf < 8; mf++) {
        const int rl = wm * 128 + mf * 16 + q * 4;
        #pragma unroll
        for (int r = 0; r < 4; r++) {
            const int g = m0 + rl + r;
            if (g < count) {
                const int token = row_token[rbase + g];
                const int slot  = row_slot[rbase + g];
                const float wgt_ = row_weight[rbase + g];
                float* orow = contrib + ((size_t)slot * T_TOK + token) * D_DIM + n0;
                #pragma unroll
                for (int nf = 0; nf < 2; nf++) {
                    const int col = wn * 32 + nf * 16 + fr;
                    orow[col] = wgt_ * (acc[mf][nf][r] + b2p[col]);
                }
            }
        }
    }
}

__global__ void k_combine(const float* __restrict__ contrib, float* __restrict__ out) {
    int i = blockIdx.x * blockDim.x + threadIdx.x;
    const f32x4* c0 = (const f32x4*)contrib;
    const f32x4* c1 = c0 + ((size_t)T_TOK * D_DIM / 4);
    f32x4* o = (f32x4*)out;
    o[i] = c0[i] + c1[i];
}

// ---------------- launch ----------------

extern "C" void kernel_launch(void* const* d_in, const int* in_sizes, int n_in,
                              void* d_out, int out_size, void* d_ws, size_t ws_size,
                              hipStream_t stream)
{
    (void)in_sizes; (void)n_in; (void)out_size; (void)ws_size;
    const float* x  = (const float*)d_in[0];
    const float* Wr = (const float*)d_in[1];
    const float* W1 = (const float*)d_in[2];
    const float* b1 = (const float*)d_in[3];
    const float* Wg = (const float*)d_in[4];
    const float* bg = (const float*)d_in[5];
    const float* W2 = (const float*)d_in[6];
    const float* b2 = (const float*)d_in[7];
    float* out = (float*)d_out;

    char* ws = (char*)d_ws;
    u16* xbf = (u16*)ws;             ws += (size_t)T_TOK * D_DIM * sizeof(u16);
    u16* hg = (u16*)ws;              ws += (size_t)NROWS * FF_DIM * sizeof(u16);
    float* contrib = (float*)ws;     ws += (size_t)2 * T_TOK * D_DIM * sizeof(float);
    int* tok_e = (int*)ws;           ws += (size_t)T_TOK * 2 * sizeof(int);
    float* tok_w = (float*)ws;       ws += (size_t)T_TOK * 2 * sizeof(float);
    int* row_token = (int*)ws;       ws += (size_t)NROWS * sizeof(int);
    int* row_slot = (int*)ws;        ws += (size_t)NROWS * sizeof(int);
    float* row_weight = (float*)ws;  ws += (size_t)NROWS * sizeof(float);
    int* cnt = (int*)ws;             ws += 8 * sizeof(int);
    int* basep = (int*)ws;           ws += 8 * sizeof(int);
    int* cursor = (int*)ws;          ws += 8 * sizeof(int);
    float* probsum = (float*)ws;     ws += 8 * sizeof(float);
    int* nt1 = (int*)ws;             ws += sizeof(int);
    int* te1 = (int*)ws;             ws += MAXT1 * sizeof(int);
    int* tm1 = (int*)ws;             ws += MAXT1 * sizeof(int);

    k_init<<<1, 64, 0, stream>>>(cnt, probsum);
    k_cvt_x<<<(T_TOK * D_DIM / 8) / 256, 256, 0, stream>>>(x, xbf);
    k_router<<<T_TOK / 4, 256, 0, stream>>>(x, Wr, tok_e, tok_w, cnt, probsum);
    k_prefix<<<1, 64, 0, stream>>>(cnt, probsum, basep, cursor, out + (size_t)T_TOK * D_DIM,
                                   nt1, te1, tm1);
    k_assign<<<T_TOK / 256, 256, 0, stream>>>(tok_e, tok_w, basep, cursor, row_token, row_slot, row_weight);
    k_pass1<<<dim3(FF_DIM / 128, MAXT1), 512, 0, stream>>>(xbf, W1, Wg, b1, bg, cnt, basep, row_token,
                                                           nt1, te1, tm1, hg);
    k_pass2<<<dim3(MAXT1, D_DIM / 128), 512, 0, stream>>>(hg, W2, b2, cnt, basep, row_token, row_slot, row_weight,
                                                          nt1, te1, tm1, contrib);
    k_combine<<<(T_TOK * D_DIM / 4) / 256, 256, 0, stream>>>(contrib, out);
}

// Round 17
// 467.240 us; speedup vs baseline: 1.1065x; 1.0719x over previous
//
#include <hip/hip_runtime.h>
#include <hip/hip_bf16.h>
#include <math.h>

#define T_TOK 4096
#define D_DIM 1024
#define E_EXP 8
#define FF_DIM 4096
#define NROWS (T_TOK * 2)
#define MAXT1 40   // max m-tiles (BM=256): 8192/256 + 8
#define MAXT2 72   // max m-tiles (BM=128): 8192/128 + 8

typedef unsigned short u16;
typedef unsigned int u32;
typedef __attribute__((ext_vector_type(8))) short bf16x8;
typedef __attribute__((ext_vector_type(4))) float f32x4;
typedef __attribute__((ext_vector_type(2))) unsigned int u32x2;
typedef __attribute__((ext_vector_type(4))) short s16x4;

__device__ __forceinline__ u16 f2bf(float f) {
    union { float f; unsigned u; } v; v.f = f;
    unsigned r = v.u + 0x7FFFu + ((v.u >> 16) & 1u);
    return (u16)(r >> 16);
}

typedef const __attribute__((address_space(1))) u32* gas1_t;
typedef __attribute__((address_space(3))) u32* las3_t;
#define GLOAD16(g, l) __builtin_amdgcn_global_load_lds((gas1_t)(const void*)(g), (las3_t)(void*)(l), 16, 0, 0)
#define MFMA(a, b, c) __builtin_amdgcn_mfma_f32_16x16x32_bf16((a), (b), (c), 0, 0, 0)
#define CVTPK(dst, lo, hi) asm("v_cvt_pk_bf16_f32 %0, %1, %2" : "=v"(dst) : "v"(lo), "v"(hi))
#define CFENCE() asm volatile("" ::: "memory")
// B-tile swizzle for fused pass1: sigma(row) = (row ^ (row>>2)) & 7.
#define SIGB(r) (((r) ^ ((r) >> 2)) & 7)

// ---------------- small kernels ----------------

__global__ void k_init(int* cnt, float* probsum) {
    int i = threadIdx.x;
    if (i < E_EXP) { cnt[i] = 0; probsum[i] = 0.f; }
}

__global__ __launch_bounds__(256) void k_router(
    const float* __restrict__ x, const float* __restrict__ Wr,
    int* __restrict__ tok_e, float* __restrict__ tok_w,
    int* __restrict__ cnt, float* __restrict__ probsum)
{
    __shared__ float bp[E_EXP];
    __shared__ int   bc[E_EXP];
    const int tid = threadIdx.x;
    if (tid < E_EXP) { bp[tid] = 0.f; bc[tid] = 0; }
    __syncthreads();
    const int wave = tid >> 6, lane = tid & 63;
    const int t = blockIdx.x * 4 + wave;
    const float* xt = x + (size_t)t * D_DIM;
    float a[E_EXP] = {0.f,0.f,0.f,0.f,0.f,0.f,0.f,0.f};
    for (int j = lane; j < D_DIM; j += 64) {
        float xv = xt[j];
        #pragma unroll
        for (int e = 0; e < E_EXP; e++) a[e] = fmaf(xv, Wr[e * D_DIM + j], a[e]);
    }
    #pragma unroll
    for (int e = 0; e < E_EXP; e++) {
        #pragma unroll
        for (int off = 32; off; off >>= 1) a[e] += __shfl_xor(a[e], off, 64);
    }
    if (lane == 0) {
        float mx = a[0];
        #pragma unroll
        for (int e = 1; e < E_EXP; e++) mx = fmaxf(mx, a[e]);
        float p[E_EXP], s = 0.f;
        #pragma unroll
        for (int e = 0; e < E_EXP; e++) { p[e] = expf(a[e] - mx); s += p[e]; }
        float inv = 1.f / s;
        #pragma unroll
        for (int e = 0; e < E_EXP; e++) { p[e] *= inv; atomicAdd(&bp[e], p[e]); }
        int e0 = 0; float v0 = p[0];
        #pragma unroll
        for (int e = 1; e < E_EXP; e++) if (p[e] > v0) { v0 = p[e]; e0 = e; }
        int e1 = -1; float v1 = -1.f;
        #pragma unroll
        for (int e = 0; e < E_EXP; e++) if (e != e0 && p[e] > v1) { v1 = p[e]; e1 = e; }
        float sv = v0 + v1 + 1e-6f;
        tok_e[2*t] = e0; tok_e[2*t+1] = e1;
        tok_w[2*t] = v0 / sv; tok_w[2*t+1] = v1 / sv;
        atomicAdd(&bc[e0], 1); atomicAdd(&bc[e1], 1);
    }
    __syncthreads();
    if (tid < E_EXP) { atomicAdd(&cnt[tid], bc[tid]); atomicAdd(&probsum[tid], bp[tid]); }
}

__global__ void k_prefix(const int* __restrict__ cnt, const float* __restrict__ probsum,
                         int* __restrict__ basep, int* __restrict__ cursor,
                         float* __restrict__ out_lb,
                         int* __restrict__ nt1, int* __restrict__ te1, int* __restrict__ tm1,
                         int* __restrict__ nt2, int* __restrict__ te2, int* __restrict__ tm2)
{
    if (threadIdx.x == 0) {
        int b = 0; float lb = 0.f;
        for (int e = 0; e < E_EXP; e++) {
            basep[e] = b; b += cnt[e];
            lb += ((float)cnt[e] / (8192.f + 1e-6f)) * probsum[e];
        }
        *out_lb = lb * (float)E_EXP;
        int n1 = 0, n2 = 0;
        for (int e = 0; e < E_EXP; e++) {
            for (int m = 0; m < cnt[e]; m += 256) { te1[n1] = e; tm1[n1] = m; n1++; }
            for (int m = 0; m < cnt[e]; m += 128) { te2[n2] = e; tm2[n2] = m; n2++; }
        }
        *nt1 = n1; *nt2 = n2;
    }
    if (threadIdx.x < E_EXP) cursor[threadIdx.x] = 0;
}

__global__ void k_assign(const int* __restrict__ tok_e, const float* __restrict__ tok_w,
                         const int* __restrict__ basep, int* __restrict__ cursor,
                         int* __restrict__ row_token, int* __restrict__ row_slot,
                         float* __restrict__ row_weight)
{
    int t = blockIdx.x * blockDim.x + threadIdx.x;
    if (t >= T_TOK) return;
    #pragma unroll
    for (int k = 0; k < 2; k++) {
        int e = tok_e[2*t + k];
        int pos = basep[e] + atomicAdd(&cursor[e], 1);
        row_token[pos] = t; row_slot[pos] = k; row_weight[pos] = tok_w[2*t + k];
    }
}

__global__ __launch_bounds__(256) void k_cvt_x(const float* __restrict__ in, u16* __restrict__ out) {
    size_t i = ((size_t)blockIdx.x * 256 + threadIdx.x) * 8;
    f32x4 a = *(const f32x4*)(in + i);
    f32x4 b = *(const f32x4*)(in + i + 4);
    bf16x8 o;
    #pragma unroll
    for (int j = 0; j < 4; j++) { o[j] = (short)f2bf(a[j]); o[j + 4] = (short)f2bf(b[j]); }
    *(bf16x8*)(out + i) = o;
}

// W2 prepass: fp32 [E][FF][D] -> bf16 [E][D][FF] (tile transpose)
__global__ __launch_bounds__(256) void k_cvt_w2(const float* __restrict__ W2, u16* __restrict__ w2t) {
    __shared__ u16 t[64][68];
    const float* in = W2 + (size_t)blockIdx.z * FF_DIM * D_DIM;
    u16* out = w2t + (size_t)blockIdx.z * FF_DIM * D_DIM;
    const int R = FF_DIM, C = D_DIM;
    const int r0 = blockIdx.y * 64, c0 = blockIdx.x * 64;
    const int tid = threadIdx.x;
    const int lr = tid >> 4, lc = (tid & 15) * 4;
    #pragma unroll
    for (int i = 0; i < 4; i++) {
        const int r = lr + i * 16;
        f32x4 v = *(const f32x4*)(in + (size_t)(r0 + r) * C + c0 + lc);
        s16x4 w;
        #pragma unroll
        for (int j = 0; j < 4; j++) w[j] = (short)f2bf(v[j]);
        *(s16x4*)&t[r][lc] = w;
    }
    __syncthreads();
    #pragma unroll
    for (int i = 0; i < 4; i++) {
        const int c = lr + i * 16;
        s16x4 w;
        #pragma unroll
        for (int j = 0; j < 4; j++) w[j] = (short)t[lc + j][c];
        *(s16x4*)(out + (size_t)(c0 + c) * R + r0 + lc) = w;
    }
}

// ---------------- pass 1: hg = silu(x@Wg) * (x@W1) ----------------
// Unchanged from R15/R16 (fused fp32-weight transpose-convert, SIGB swizzle).

__global__ __launch_bounds__(512, 2) void k_pass1(
    const u16* __restrict__ xbf,
    const float* __restrict__ W1, const float* __restrict__ Wg,
    const float* __restrict__ b1v, const float* __restrict__ bgv,
    const int* __restrict__ cnt, const int* __restrict__ basep,
    const int* __restrict__ row_token,
    const int* __restrict__ ntp, const int* __restrict__ te, const int* __restrict__ tm,
    u16* __restrict__ hg)
{
    const int ty = blockIdx.y;
    if (ty >= *ntp) return;
    const int e = te[ty];
    const int m0 = tm[ty];
    const int count = cnt[e];
    const int rbase = basep[e];
    const int n0 = blockIdx.x * 128;

    __shared__ __align__(16) u16 LDS[2 * 32768];

    const int tid = threadIdx.x;
    const int l = tid & 63;
    const int w = tid >> 6;

    const int rb = tid >> 3;
    const int swA = ((tid & 7) ^ ((tid >> 3) & 7)) * 8;
    const u16* sA[4];
    #pragma unroll
    for (int s = 0; s < 4; s++) {
        int g = m0 + rb + s * 64; if (g > count - 1) g = count - 1;
        sA[s] = xbf + (size_t)row_token[rbase + g] * D_DIM + swA;
    }

    const int nq = tid & 31;
    const int kq = tid >> 5;
    const float* pBh = W1 + ((size_t)e * D_DIM + kq * 4) * FF_DIM + n0 + nq * 4;
    const float* pBg = Wg + ((size_t)e * D_DIM + kq * 4) * FF_DIM + n0 + nq * 4;
    const int cW = kq >> 1;
    const int offW = (kq & 1) * 4;
    int wdst[4];
    #pragma unroll
    for (int j = 0; j < 4; j++) {
        const int row = nq * 4 + j;
        wdst[j] = row * 64 + (cW ^ SIGB(row)) * 8 + offW;
    }

    const int wm = w >> 2, wn = w & 3;
    const int fr = l & 15, q = l >> 4;
    const int s7 = fr & 7;

    f32x4 acc_h[8][2], acc_g[8][2];
    const f32x4 z4 = {0.f, 0.f, 0.f, 0.f};
    #pragma unroll
    for (int mf = 0; mf < 8; mf++)
        #pragma unroll
        for (int nf = 0; nf < 2; nf++) { acc_h[mf][nf] = z4; acc_g[mf][nf] = z4; }

    f32x4 vb0, vb1, vb2, vb3;

    #define LOADB1(P, K0) do { \
        const float* p_ = (P) + (size_t)(K0) * FF_DIM; \
        vb0 = *(const f32x4*)(p_); \
        vb1 = *(const f32x4*)(p_ + FF_DIM); \
        vb2 = *(const f32x4*)(p_ + 2 * FF_DIM); \
        vb3 = *(const f32x4*)(p_ + 3 * FF_DIM); \
    } while (0)

    #define CVTW1(BASE) do { \
        _Pragma("unroll") \
        for (int j = 0; j < 4; j++) { \
            u32 lo_, hi_; u32x2 wv_; \
            CVTPK(lo_, vb0[j], vb1[j]); \
            CVTPK(hi_, vb2[j], vb3[j]); \
            wv_.x = lo_; wv_.y = hi_; \
            *(u32x2*)&LDS[(BASE) + wdst[j]] = wv_; \
        } \
    } while (0)

    #define STAGE_A1(B, K0) do { \
        _Pragma("unroll") \
        for (int s = 0; s < 4; s++) \
            GLOAD16(sA[s] + (K0), &LDS[(B) * 32768 + s * 4096 + tid * 8]); \
    } while (0)

    auto COMP = [&](int kk, int ab) {
        const int rsA = ((kk * 4 + q) ^ s7) * 8;
        const int rB0 = wn * 32 + fr, rB1 = wn * 32 + 16 + fr;
        const int cb0 = ((kk * 4 + q) ^ SIGB(rB0)) * 8;
        const int cb1 = ((kk * 4 + q) ^ SIGB(rB1)) * 8;
        bf16x8 bh0 = *(const bf16x8*)&LDS[ab + 16384 + rB0 * 64 + cb0];
        bf16x8 bg0 = *(const bf16x8*)&LDS[ab + 24576 + rB0 * 64 + cb0];
        bf16x8 bh1 = *(const bf16x8*)&LDS[ab + 16384 + rB1 * 64 + cb1];
        bf16x8 bg1 = *(const bf16x8*)&LDS[ab + 24576 + rB1 * 64 + cb1];
        #define LDA1(i) (*(const bf16x8*)&LDS[ab + (wm * 128 + (i) * 16 + fr) * 64 + rsA])
        #define MF4(areg, i) do { \
            __builtin_amdgcn_s_setprio(1); \
            acc_h[i][0] = MFMA(areg, bh0, acc_h[i][0]); \
            acc_h[i][1] = MFMA(areg, bh1, acc_h[i][1]); \
            acc_g[i][0] = MFMA(areg, bg0, acc_g[i][0]); \
            acc_g[i][1] = MFMA(areg, bg1, acc_g[i][1]); \
            __builtin_amdgcn_s_setprio(0); } while (0)
        bf16x8 aA = LDA1(0);
        bf16x8 aB = LDA1(1);
        bf16x8 aC;
        aC = LDA1(2); MF4(aA, 0);
        aA = LDA1(3); MF4(aB, 1);
        aB = LDA1(4); MF4(aC, 2);
        aC = LDA1(5); MF4(aA, 3);
        aA = LDA1(6); MF4(aB, 4);
        aB = LDA1(7); MF4(aC, 5);
        MF4(aA, 6);
        MF4(aB, 7);
        #undef LDA1
        #undef MF4
    };

    const int NT = D_DIM / 64;   // 16
    LOADB1(pBh, 0);
    CVTW1(0 + 16384);
    STAGE_A1(0, 0);
    LOADB1(pBg, 0);
    CVTW1(0 + 24576);
    asm volatile("s_waitcnt vmcnt(0) lgkmcnt(0)" ::: "memory");
    __builtin_amdgcn_s_barrier();
    CFENCE();

    int b = 0;
    #pragma unroll 1
    for (int t = 0; t < NT; ++t) {
        const int ab = b * 32768;
        const int nboff = (b ^ 1) * 32768;
        const int kN = (t + 1 < NT ? t + 1 : NT - 1) * 64;
        LOADB1(pBh, kN);
        COMP(0, ab);
        CVTW1(nboff + 16384);
        STAGE_A1(b ^ 1, kN);
        LOADB1(pBg, kN);
        COMP(1, ab);
        CVTW1(nboff + 24576);
        asm volatile("s_waitcnt vmcnt(0) lgkmcnt(0)" ::: "memory");
        __builtin_amdgcn_s_barrier();
        CFENCE();
        b ^= 1;
    }
    asm volatile("s_waitcnt vmcnt(0)" ::: "memory");
    #undef LOADB1
    #undef CVTW1
    #undef STAGE_A1

    const float* b1p = b1v + (size_t)e * FF_DIM + n0;
    const float* bgp = bgv + (size_t)e * FF_DIM + n0;
    #pragma unroll
    for (int mf = 0; mf < 8; mf++) {
        const int rl = wm * 128 + mf * 16 + q * 4;
        #pragma unroll
        for (int r = 0; r < 4; r++) {
            const int g = m0 + rl + r;
            if (g < count) {
                u16* orow = hg + (size_t)(rbase + g) * FF_DIM + n0;
                #pragma unroll
                for (int nf = 0; nf < 2; nf++) {
                    const int col = wn * 32 + nf * 16 + fr;
                    float hv = acc_h[mf][nf][r] + b1p[col];
                    float gv = acc_g[mf][nf][r] + bgp[col];
                    float sig = 1.f / (1.f + expf(-gv));
                    orow[col] = f2bf(gv * sig * hv);
                }
            }
        }
    }
}

// ---------------- pass 2: contrib[slot] = w * (hg @ W2 + b2) ----------------
// R11 version byte-for-byte: BM=128 BN=128 BK=64, 4 waves (2Mx2N, 64x64/wave),
// 2x32KB dbuf -> 2 blocks/CU, depth-1 counted vmcnt(8), sigma(r)=r&7 swizzle,
// both operands bf16 via global_load_lds (w2t prepass).

__global__ __launch_bounds__(256, 2) void k_pass2(
    const u16* __restrict__ hg,
    const u16* __restrict__ w2t, const float* __restrict__ b2v,
    const int* __restrict__ cnt, const int* __restrict__ basep,
    const int* __restrict__ row_token, const int* __restrict__ row_slot,
    const float* __restrict__ row_weight,
    const int* __restrict__ ntp, const int* __restrict__ te, const int* __restrict__ tm,
    float* __restrict__ contrib)
{
    const int ty = blockIdx.y;
    if (ty >= *ntp) return;
    const int e = te[ty];
    const int m0 = tm[ty];
    const int count = cnt[e];
    const int rbase = basep[e];
    const int n0 = blockIdx.x * 128;

    // per buffer (16384 elems = 32 KB): A[128x64] @0, B[128x64] @8192
    __shared__ __align__(16) u16 LDS[2 * 16384];

    const int tid = threadIdx.x;
    const int l = tid & 63;
    const int w = tid >> 6;

    const int rb = tid >> 3;                        // 0..31
    const int sw0 = ((tid & 7) ^ ((tid >> 3) & 7)) * 8;
    const u16* sA[4];
    #pragma unroll
    for (int s = 0; s < 4; s++) {
        int g = m0 + rb + s * 32; if (g > count - 1) g = count - 1;
        sA[s] = hg + (size_t)(rbase + g) * FF_DIM + sw0;
    }
    const u16* sB[4];
    #pragma unroll
    for (int s = 0; s < 4; s++)
        sB[s] = w2t + ((size_t)e * D_DIM + (size_t)(n0 + rb + s * 32)) * FF_DIM + sw0;

    const int wm = w >> 1, wn = w & 1;   // 2M x 2N
    const int fr = l & 15, q = l >> 4;
    const int s7 = fr & 7;

    f32x4 acc[4][4];
    const f32x4 z4 = {0.f, 0.f, 0.f, 0.f};
    #pragma unroll
    for (int mf = 0; mf < 4; mf++)
        #pragma unroll
        for (int nf = 0; nf < 4; nf++) acc[mf][nf] = z4;

    auto STAGE = [&](int b, int k0) {
        #pragma unroll
        for (int s = 0; s < 4; s++)
            GLOAD16(sA[s] + k0, &LDS[b * 16384 + s * 2048 + tid * 8]);
        #pragma unroll
        for (int s = 0; s < 4; s++)
            GLOAD16(sB[s] + k0, &LDS[b * 16384 + 8192 + s * 2048 + tid * 8]);
    };

    const int NT = FF_DIM / 64;   // 64
    STAGE(0, 0);
    int cur = 0;
    #pragma unroll 1
    for (int t = 0; t < NT; ++t) {
        if (t + 1 < NT) {
            STAGE(cur ^ 1, (t + 1) * 64);
            asm volatile("s_waitcnt vmcnt(8)" ::: "memory");
        } else {
            asm volatile("s_waitcnt vmcnt(0)" ::: "memory");
        }
        __builtin_amdgcn_s_barrier();
        CFENCE();
        const int ab = cur * 16384;
        #pragma unroll
        for (int kk = 0; kk < 2; kk++) {
            const int rs = ((kk * 4 + q) ^ s7) * 8;
            bf16x8 a[4], bb[4];
            #pragma unroll
            for (int mf = 0; mf < 4; mf++)
                a[mf] = *(const bf16x8*)&LDS[ab + (wm * 64 + mf * 16 + fr) * 64 + rs];
            #pragma unroll
            for (int nf = 0; nf < 4; nf++)
                bb[nf] = *(const bf16x8*)&LDS[ab + 8192 + (wn * 64 + nf * 16 + fr) * 64 + rs];
            __builtin_amdgcn_s_setprio(1);
            #pragma unroll
            for (int mf = 0; mf < 4; mf++)
                #pragma unroll
                for (int nf = 0; nf < 4; nf++)
                    acc[mf][nf] = MFMA(a[mf], bb[nf], acc[mf][nf]);
            __builtin_amdgcn_s_setprio(0);
        }
        CFENCE();
        __builtin_amdgcn_s_barrier();
        cur ^= 1;
    }

    const float* b2p = b2v + (size_t)e * D_DIM + n0;
    #pragma unroll
    for (int mf = 0; mf < 4; mf++) {
        const int rl = wm * 64 + mf * 16 + q * 4;
        #pragma unroll
        for (int r = 0; r < 4; r++) {
            const int g = m0 + rl + r;
            if (g < count) {
                const int token = row_token[rbase + g];
                const int slot  = row_slot[rbase + g];
                const float wgt_ = row_weight[rbase + g];
                float* orow = contrib + ((size_t)slot * T_TOK + token) * D_DIM + n0;
                #pragma unroll
                for (int nf = 0; nf < 4; nf++) {
                    const int col = wn * 64 + nf * 16 + fr;
                    orow[col] = wgt_ * (acc[mf][nf][r] + b2p[col]);
                }
            }
        }
    }
}

__global__ void k_combine(const float* __restrict__ contrib, float* __restrict__ out) {
    int i = blockIdx.x * blockDim.x + threadIdx.x;
    const f32x4* c0 = (const f32x4*)contrib;
    const f32x4* c1 = c0 + ((size_t)T_TOK * D_DIM / 4);
    f32x4* o = (f32x4*)out;
    o[i] = c0[i] + c1[i];
}

// ---------------- launch ----------------

extern "C" void kernel_launch(void* const* d_in, const int* in_sizes, int n_in,
                              void* d_out, int out_size, void* d_ws, size_t ws_size,
                              hipStream_t stream)
{
    (void)in_sizes; (void)n_in; (void)out_size; (void)ws_size;
    const float* x  = (const float*)d_in[0];
    const float* Wr = (const float*)d_in[1];
    const float* W1 = (const float*)d_in[2];
    const float* b1 = (const float*)d_in[3];
    const float* Wg = (const float*)d_in[4];
    const float* bg = (const float*)d_in[5];
    const float* W2 = (const float*)d_in[6];
    const float* b2 = (const float*)d_in[7];
    float* out = (float*)d_out;

    char* ws = (char*)d_ws;
    u16* xbf = (u16*)ws;             ws += (size_t)T_TOK * D_DIM * sizeof(u16);
    u16* w2t = (u16*)ws;             ws += (size_t)E_EXP * D_DIM * FF_DIM * sizeof(u16);
    u16* hg = (u16*)ws;              ws += (size_t)NROWS * FF_DIM * sizeof(u16);
    float* contrib = (float*)ws;     ws += (size_t)2 * T_TOK * D_DIM * sizeof(float);
    int* tok_e = (int*)ws;           ws += (size_t)T_TOK * 2 * sizeof(int);
    float* tok_w = (float*)ws;       ws += (size_t)T_TOK * 2 * sizeof(float);
    int* row_token = (int*)ws;       ws += (size_t)NROWS * sizeof(int);
    int* row_slot = (int*)ws;        ws += (size_t)NROWS * sizeof(int);
    float* row_weight = (float*)ws;  ws += (size_t)NROWS * sizeof(float);
    int* cnt = (int*)ws;             ws += 8 * sizeof(int);
    int* basep = (int*)ws;           ws += 8 * sizeof(int);
    int* cursor = (int*)ws;          ws += 8 * sizeof(int);
    float* probsum = (float*)ws;     ws += 8 * sizeof(float);
    int* nt1 = (int*)ws;             ws += sizeof(int);
    int* nt2 = (int*)ws;             ws += sizeof(int);
    int* te1 = (int*)ws;             ws += MAXT1 * sizeof(int);
    int* tm1 = (int*)ws;             ws += MAXT1 * sizeof(int);
    int* te2 = (int*)ws;             ws += MAXT2 * sizeof(int);
    int* tm2 = (int*)ws;             ws += MAXT2 * sizeof(int);

    k_init<<<1, 64, 0, stream>>>(cnt, probsum);
    k_cvt_x<<<(T_TOK * D_DIM / 8) / 256, 256, 0, stream>>>(x, xbf);
    k_cvt_w2<<<dim3(D_DIM / 64, FF_DIM / 64, E_EXP), 256, 0, stream>>>(W2, w2t);
    k_router<<<T_TOK / 4, 256, 0, stream>>>(x, Wr, tok_e, tok_w, cnt, probsum);
    k_prefix<<<1, 64, 0, stream>>>(cnt, probsum, basep, cursor, out + (size_t)T_TOK * D_DIM,
                                   nt1, te1, tm1, nt2, te2, tm2);
    k_assign<<<T_TOK / 256, 256, 0, stream>>>(tok_e, tok_w, basep, cursor, row_token, row_slot, row_weight);
    k_pass1<<<dim3(FF_DIM / 128, MAXT1), 512, 0, stream>>>(xbf, W1, Wg, b1, bg, cnt, basep, row_token,
                                                           nt1, te1, tm1, hg);
    k_pass2<<<dim3(D_DIM / 128, MAXT2), 256, 0, stream>>>(hg, w2t, b2, cnt, basep, row_token, row_slot, row_weight,
                                                          nt2, te2, tm2, contrib);
    k_combine<<<(T_TOK * D_DIM / 4) / 256, 256, 0, stream>>>(contrib, out);
}